// Round 1
// baseline (1249.120 us; speedup 1.0000x reference)
//
#include <hip/hip_runtime.h>

// HMM forward: B=64, T=2048, N=64, D=128
// ws layout (float offsets):
//   P       @ 0      (64*64)     transition probs exp(log_softmax)
//   Wc      @ 4096   (256*64)    k<128: -0.5*inv_var[d][n] ; k>=128: mean*inv_var[d][n]   ([k][n])
//   cn      @ 20480  (64)        -0.5*(t3 + D*log2pi)
//   log_pi  @ 20544  (64)
//   part    @ 20608  (64)        per-batch final logsumexp
//   logb    @ 20736  (64*2048*64 = 8388608)   emission logprobs
// total ~33.6 MB

constexpr int P_OFF    = 0;
constexpr int WC_OFF   = 4096;
constexpr int CN_OFF   = 20480;
constexpr int LPI_OFF  = 20544;
constexpr int PART_OFF = 20608;
constexpr int LOGB_OFF = 20736;

__device__ inline float wave_max(float v) {
  #pragma unroll
  for (int off = 1; off < 64; off <<= 1) v = fmaxf(v, __shfl_xor(v, off));
  return v;
}
__device__ inline float wave_sum(float v) {
  #pragma unroll
  for (int off = 1; off < 64; off <<= 1) v += __shfl_xor(v, off);
  return v;
}

// ---------------- setup: P, log_pi, Wc, cn ----------------
__global__ void setup_kernel(const float* __restrict__ trans,
                             const float* __restrict__ priors,
                             const float* __restrict__ means,
                             const float* __restrict__ log_vars,
                             float* __restrict__ ws) {
  float* P   = ws + P_OFF;
  float* Wc  = ws + WC_OFF;
  float* cn  = ws + CN_OFF;
  float* lpi = ws + LPI_OFF;
  int tid = threadIdx.x, lane = tid & 63, w = tid >> 6;

  // log_softmax over rows of transition -> P = exp(log_A)
  for (int r = 0; r < 16; ++r) {
    int i = w * 16 + r;
    float x = trans[i * 64 + lane];
    float m = wave_max(x);
    float s = wave_sum(__expf(x - m));
    float lse = m + __logf(s);
    P[i * 64 + lane] = __expf(x - lse);
  }
  if (w == 0) {
    float x = priors[lane];
    float m = wave_max(x);
    float s = wave_sum(__expf(x - m));
    lpi[lane] = x - (m + __logf(s));
  }
  // combined GEMM weights, [k][n] layout (n fastest)
  for (int idx = tid; idx < 16384; idx += 256) {
    int k = idx >> 6, n = idx & 63;
    int d = (k < 128) ? k : (k - 128);
    float iv = __expf(-log_vars[n * 128 + d]);
    Wc[idx] = (k < 128) ? (-0.5f * iv) : (means[n * 128 + d] * iv);
  }
  // cn[n] = -0.5*(sum_d (mu^2*iv + lv) + D*log(2pi))
  if (tid < 64) {
    int n = tid;
    float s = 0.f;
    for (int d = 0; d < 128; ++d) {
      float lv = log_vars[n * 128 + d];
      float mu = means[n * 128 + d];
      s += mu * mu * __expf(-lv) + lv;
    }
    cn[n] = -0.5f * (s + 128.0f * 1.8378770664093453f);
  }
}

// ---------------- emissions: log_b = A @ Wc + cn ----------------
// block: 64 rows x 64 n, K split into two 128-halves (x^2 half, x half).
// LDS: As (x values, [d][row], 32KB) + Ws (one K-half of Wc, [k][n], 32KB) = 64KB.
__global__ __launch_bounds__(256) void emis_kernel(const float* __restrict__ X,
                                                   const float* __restrict__ ws,
                                                   float* __restrict__ logb) {
  const float* Wc = ws + WC_OFF;
  const float* cn = ws + CN_OFF;
  __shared__ float As[128 * 64];
  __shared__ float Ws[128 * 64];
  int tid = threadIdx.x;
  int r0 = blockIdx.x * 64;

  // stage X tile (x only)
  #pragma unroll
  for (int c = 0; c < 8; ++c) {
    int flat = c * 1024 + tid * 4;
    int row = flat >> 7, d = flat & 127;
    float4 xv = *reinterpret_cast<const float4*>(&X[(size_t)(r0 + row) * 128 + d]);
    float xs[4] = {xv.x, xv.y, xv.z, xv.w};
    #pragma unroll
    for (int i = 0; i < 4; ++i) As[(d + i) * 64 + row] = xs[i];
  }
  // stage W half 0 (-0.5*inv_var)
  #pragma unroll
  for (int c = 0; c < 8; ++c) {
    int flat = c * 1024 + tid * 4;
    *reinterpret_cast<float4*>(&Ws[flat]) = *reinterpret_cast<const float4*>(&Wc[flat]);
  }
  __syncthreads();

  int tr = tid & 15, tc = tid >> 4;   // n-group, row-group
  float acc[4][4] = {};

  // phase 0: x^2 terms
  #pragma unroll 4
  for (int d = 0; d < 128; ++d) {
    float4 a4 = *reinterpret_cast<const float4*>(&As[d * 64 + tc * 4]);
    float4 w4 = *reinterpret_cast<const float4*>(&Ws[d * 64 + tr * 4]);
    float av[4] = {a4.x * a4.x, a4.y * a4.y, a4.z * a4.z, a4.w * a4.w};
    float wv[4] = {w4.x, w4.y, w4.z, w4.w};
    #pragma unroll
    for (int i = 0; i < 4; ++i)
      #pragma unroll
      for (int j = 0; j < 4; ++j) acc[i][j] = fmaf(av[i], wv[j], acc[i][j]);
  }
  __syncthreads();
  // stage W half 1 (mean*inv_var)
  #pragma unroll
  for (int c = 0; c < 8; ++c) {
    int flat = c * 1024 + tid * 4;
    *reinterpret_cast<float4*>(&Ws[flat]) = *reinterpret_cast<const float4*>(&Wc[8192 + flat]);
  }
  __syncthreads();
  // phase 1: x terms
  #pragma unroll 4
  for (int d = 0; d < 128; ++d) {
    float4 a4 = *reinterpret_cast<const float4*>(&As[d * 64 + tc * 4]);
    float4 w4 = *reinterpret_cast<const float4*>(&Ws[d * 64 + tr * 4]);
    float av[4] = {a4.x, a4.y, a4.z, a4.w};
    float wv[4] = {w4.x, w4.y, w4.z, w4.w};
    #pragma unroll
    for (int i = 0; i < 4; ++i)
      #pragma unroll
      for (int j = 0; j < 4; ++j) acc[i][j] = fmaf(av[i], wv[j], acc[i][j]);
  }

  float4 c4 = *reinterpret_cast<const float4*>(&cn[tr * 4]);
  float cv[4] = {c4.x, c4.y, c4.z, c4.w};
  #pragma unroll
  for (int i = 0; i < 4; ++i) {
    int row = r0 + tc * 4 + i;
    float4 o;
    o.x = acc[i][0] + cv[0];
    o.y = acc[i][1] + cv[1];
    o.z = acc[i][2] + cv[2];
    o.w = acc[i][3] + cv[3];
    *reinterpret_cast<float4*>(&logb[(size_t)row * 64 + tr * 4]) = o;
  }
}

// ---------------- forward recursion ----------------
// 1 block per batch, 4 waves. lane = state j. Wave w owns i in [16w,16w+16):
// holds P[i][j] in regs. Per step: m = max(alpha); w_i = exp(alpha_i - m)
// (each wave writes all 64 identical values -> benign race, no barrier);
// partial matvec; LDS reduce across the 4 waves (1 barrier, ping-pong buffer);
// alpha' = lb + m + log(v).
__global__ __launch_bounds__(256) void forward_kernel(const float* __restrict__ ws,
                                                      float* __restrict__ part) {
  const float* P    = ws + P_OFF;
  const float* lpi  = ws + LPI_OFF;
  const float* logb = ws + LOGB_OFF;
  __shared__ float w_sh[64];
  __shared__ float partial[2][64][4];

  int b = blockIdx.x;
  int tid = threadIdx.x, lane = tid & 63, wid = tid >> 6;

  float p[16];
  #pragma unroll
  for (int ii = 0; ii < 16; ++ii) p[ii] = P[(wid * 16 + ii) * 64 + lane];

  const float* lb = logb + (size_t)b * (2048 * 64);
  float alpha = lpi[lane] + lb[lane];          // t = 0
  float lb_cur = lb[64 + lane];                // t = 1
  float lb_nxt = lb[128 + lane];               // t = 2

  for (int t = 1; t < 2048; ++t) {
    float m = wave_max(alpha);
    float wv = __expf(alpha - m);
    w_sh[lane] = wv;                           // all 4 waves write identical values
    float v0 = 0.f, v1 = 0.f;
    #pragma unroll
    for (int q = 0; q < 4; ++q) {
      float4 w4 = *reinterpret_cast<const float4*>(&w_sh[wid * 16 + q * 4]);
      v0 = fmaf(w4.x, p[q * 4 + 0], v0);
      v1 = fmaf(w4.y, p[q * 4 + 1], v1);
      v0 = fmaf(w4.z, p[q * 4 + 2], v0);
      v1 = fmaf(w4.w, p[q * 4 + 3], v1);
    }
    partial[t & 1][lane][wid] = v0 + v1;
    __syncthreads();
    float4 pv = *reinterpret_cast<const float4*>(&partial[t & 1][lane][0]);
    float sv = (pv.x + pv.y) + (pv.z + pv.w);
    alpha = lb_cur + m + __logf(sv);
    lb_cur = lb_nxt;
    int tp = t + 2;
    lb_nxt = (tp < 2048) ? lb[tp * 64 + lane] : 0.f;
  }

  float m2 = wave_max(alpha);
  float s2 = wave_sum(__expf(alpha - m2));
  if (tid == 0) part[b] = m2 + __logf(s2);
}

// ---------------- final deterministic sum ----------------
__global__ void final_kernel(const float* __restrict__ part, float* __restrict__ out) {
  float v = part[threadIdx.x];
  float s = wave_sum(v);
  if (threadIdx.x == 0) out[0] = s;
}

extern "C" void kernel_launch(void* const* d_in, const int* in_sizes, int n_in,
                              void* d_out, int out_size, void* d_ws, size_t ws_size,
                              hipStream_t stream) {
  const float* X        = (const float*)d_in[0];
  const float* trans    = (const float*)d_in[1];
  const float* priors   = (const float*)d_in[2];
  const float* means    = (const float*)d_in[3];
  const float* log_vars = (const float*)d_in[4];
  float* ws  = (float*)d_ws;
  float* out = (float*)d_out;

  hipLaunchKernelGGL(setup_kernel, dim3(1), dim3(256), 0, stream,
                     trans, priors, means, log_vars, ws);
  hipLaunchKernelGGL(emis_kernel, dim3(2048), dim3(256), 0, stream,
                     X, ws, ws + LOGB_OFF);
  hipLaunchKernelGGL(forward_kernel, dim3(64), dim3(256), 0, stream,
                     ws, ws + PART_OFF);
  hipLaunchKernelGGL(final_kernel, dim3(1), dim3(64), 0, stream,
                     ws + PART_OFF, out);
}

// Round 3
// 1190.261 us; speedup vs baseline: 1.0495x; 1.0495x over previous
//
#include <hip/hip_runtime.h>

// HMM forward: B=64, T=2048, N=64, D=128
// ws layout (float offsets):
//   P       @ 0      (64*64)     transition probs exp(log_softmax)
//   Wc      @ 4096   (256*64)    k<128: -0.5*inv_var[d][n] ; k>=128: mean*inv_var[d][n]   ([k][n])
//   cn      @ 20480  (64)        -0.5*(t3 + D*log2pi)
//   log_pi  @ 20544  (64)
//   part    @ 20608  (64)        per-batch final logsumexp
//   logb    @ 20736  (64*64*2048)  emission logprobs, TRANSPOSED: [b][n][t]
// total ~33.6 MB

constexpr int P_OFF    = 0;
constexpr int WC_OFF   = 4096;
constexpr int CN_OFF   = 20480;
constexpr int LPI_OFF  = 20544;
constexpr int PART_OFF = 20608;
constexpr int LOGB_OFF = 20736;

__device__ inline float wave_max(float v) {
  #pragma unroll
  for (int off = 1; off < 64; off <<= 1) v = fmaxf(v, __shfl_xor(v, off));
  return v;
}
__device__ inline float wave_sum(float v) {
  #pragma unroll
  for (int off = 1; off < 64; off <<= 1) v += __shfl_xor(v, off);
  return v;
}
__device__ inline float read_lane(float v, int l) {
  return __uint_as_float(__builtin_amdgcn_readlane(__float_as_uint(v), l));
}

// ---------------- setup: P, log_pi, Wc, cn ----------------
__global__ void setup_kernel(const float* __restrict__ trans,
                             const float* __restrict__ priors,
                             const float* __restrict__ means,
                             const float* __restrict__ log_vars,
                             float* __restrict__ ws) {
  float* P   = ws + P_OFF;
  float* Wc  = ws + WC_OFF;
  float* cn  = ws + CN_OFF;
  float* lpi = ws + LPI_OFF;
  int tid = threadIdx.x, lane = tid & 63, w = tid >> 6;

  // log_softmax over rows of transition -> P = exp(log_A)
  for (int r = 0; r < 16; ++r) {
    int i = w * 16 + r;
    float x = trans[i * 64 + lane];
    float m = wave_max(x);
    float s = wave_sum(__expf(x - m));
    float lse = m + __logf(s);
    P[i * 64 + lane] = __expf(x - lse);
  }
  if (w == 0) {
    float x = priors[lane];
    float m = wave_max(x);
    float s = wave_sum(__expf(x - m));
    lpi[lane] = x - (m + __logf(s));
  }
  // combined GEMM weights, [k][n] layout (n fastest)
  for (int idx = tid; idx < 16384; idx += 256) {
    int k = idx >> 6, n = idx & 63;
    int d = (k < 128) ? k : (k - 128);
    float iv = __expf(-log_vars[n * 128 + d]);
    Wc[idx] = (k < 128) ? (-0.5f * iv) : (means[n * 128 + d] * iv);
  }
  // cn[n] = -0.5*(sum_d (mu^2*iv + lv) + D*log(2pi))
  if (tid < 64) {
    int n = tid;
    float s = 0.f;
    for (int d = 0; d < 128; ++d) {
      float lv = log_vars[n * 128 + d];
      float mu = means[n * 128 + d];
      s += mu * mu * __expf(-lv) + lv;
    }
    cn[n] = -0.5f * (s + 128.0f * 1.8378770664093453f);
  }
}

// ---------------- emissions: log_b = A @ Wc + cn, stored [b][n][t] ----------------
// block: 64 rows(t) x 64 n. tt = t-group (fast in tid, for coalesced [n][t] stores),
// tn = n-group.
__global__ __launch_bounds__(256) void emis_kernel(const float* __restrict__ X,
                                                   const float* __restrict__ ws,
                                                   float* __restrict__ logb) {
  const float* Wc = ws + WC_OFF;
  const float* cn = ws + CN_OFF;
  __shared__ float As[128 * 64];
  __shared__ float Ws[128 * 64];
  int tid = threadIdx.x;
  int r0 = blockIdx.x * 64;

  // stage X tile
  #pragma unroll
  for (int c = 0; c < 8; ++c) {
    int flat = c * 1024 + tid * 4;
    int row = flat >> 7, d = flat & 127;
    float4 xv = *reinterpret_cast<const float4*>(&X[(size_t)(r0 + row) * 128 + d]);
    float xs[4] = {xv.x, xv.y, xv.z, xv.w};
    #pragma unroll
    for (int i = 0; i < 4; ++i) As[(d + i) * 64 + row] = xs[i];
  }
  // stage W half 0 (-0.5*inv_var)
  #pragma unroll
  for (int c = 0; c < 8; ++c) {
    int flat = c * 1024 + tid * 4;
    *reinterpret_cast<float4*>(&Ws[flat]) = *reinterpret_cast<const float4*>(&Wc[flat]);
  }
  __syncthreads();

  int tt = tid & 15, tn = tid >> 4;   // t-row-group (fast), n-group
  float acc[4][4] = {};               // [t-offset][n-offset]

  // phase 0: x^2 terms
  #pragma unroll 4
  for (int d = 0; d < 128; ++d) {
    float4 a4 = *reinterpret_cast<const float4*>(&As[d * 64 + tt * 4]);
    float4 w4 = *reinterpret_cast<const float4*>(&Ws[d * 64 + tn * 4]);
    float av[4] = {a4.x * a4.x, a4.y * a4.y, a4.z * a4.z, a4.w * a4.w};
    float wv[4] = {w4.x, w4.y, w4.z, w4.w};
    #pragma unroll
    for (int i = 0; i < 4; ++i)
      #pragma unroll
      for (int j = 0; j < 4; ++j) acc[i][j] = fmaf(av[i], wv[j], acc[i][j]);
  }
  __syncthreads();
  // stage W half 1 (mean*inv_var)
  #pragma unroll
  for (int c = 0; c < 8; ++c) {
    int flat = c * 1024 + tid * 4;
    *reinterpret_cast<float4*>(&Ws[flat]) = *reinterpret_cast<const float4*>(&Wc[8192 + flat]);
  }
  __syncthreads();
  // phase 1: x terms
  #pragma unroll 4
  for (int d = 0; d < 128; ++d) {
    float4 a4 = *reinterpret_cast<const float4*>(&As[d * 64 + tt * 4]);
    float4 w4 = *reinterpret_cast<const float4*>(&Ws[d * 64 + tn * 4]);
    float av[4] = {a4.x, a4.y, a4.z, a4.w};
    float wv[4] = {w4.x, w4.y, w4.z, w4.w};
    #pragma unroll
    for (int i = 0; i < 4; ++i)
      #pragma unroll
      for (int j = 0; j < 4; ++j) acc[i][j] = fmaf(av[i], wv[j], acc[i][j]);
  }

  float4 c4 = *reinterpret_cast<const float4*>(&cn[tn * 4]);
  float cv[4] = {c4.x, c4.y, c4.z, c4.w};
  int b_idx = r0 >> 11;
  int tbase = (r0 & 2047) + tt * 4;
  #pragma unroll
  for (int jj = 0; jj < 4; ++jj) {
    int n = tn * 4 + jj;
    float4 o;
    o.x = acc[0][jj] + cv[jj];
    o.y = acc[1][jj] + cv[jj];
    o.z = acc[2][jj] + cv[jj];
    o.w = acc[3][jj] + cv[jj];
    *reinterpret_cast<float4*>(&logb[(size_t)b_idx * 131072 + (size_t)n * 2048 + tbase]) = o;
  }
}

// ---------------- forward recursion (single wave per batch) ----------------
// Prob-space recursion, invariant alpha_t[j] = M + log(w[j]) (exact for ANY
// lane-uniform scaling absorbed into M).
// Per step:  y[j] = sum_i w[i]*P[i][j]   (64 readlane + 64 fmac, no LDS/barrier)
//            w'[j] = y[j] * exp(lb_t[j] - m_t);  M += m_t   (m_t data-only, off-chain)
// Bounds per step (P cols within [0.984,1.016]/64, sum_j exp(lb-m) <= 64):
//   0.0154*S <= S' <= 1.018*S  -> exact renorm every 4 steps keeps
//   S in [5.6e-8, 1.1]: no overflow/underflow ever, log/rcp args always valid.
// lb stored [b][n][t]: lane j reads float4 (4 timesteps), prefetched 2 groups
// (~8 steps ~ 2300 cyc) ahead -> HBM latency fully hidden.
__global__ __launch_bounds__(64) void forward_kernel(const float* __restrict__ ws,
                                                     float* __restrict__ part) {
  const float* P    = ws + P_OFF;
  const float* lpi  = ws + LPI_OFF;
  const float* logb = ws + LOGB_OFF;

  int b = blockIdx.x;
  int j = threadIdx.x;            // one wave: lane = state j

  // P column j resident in registers
  float p[64];
  #pragma unroll
  for (int i = 0; i < 64; ++i) p[i] = P[i * 64 + j];

  const float* lbj = logb + (size_t)b * 131072 + (size_t)j * 2048;

  float4 Av = *reinterpret_cast<const float4*>(lbj + 0);   // t 0..3
  float4 Bv = *reinterpret_cast<const float4*>(lbj + 4);   // t 4..7
  float4 Cv = *reinterpret_cast<const float4*>(lbj + 8);   // t 8..11

  float a0 = lpi[j] + Av.x;
  float M  = wave_max(a0);
  float w  = __expf(a0 - M);

#define STEP(lbv, mv) {                                        \
    float e_ = __expf((lbv) - (mv));                           \
    float ac0 = 0.f, ac1 = 0.f, ac2 = 0.f, ac3 = 0.f;          \
    _Pragma("unroll")                                          \
    for (int i_ = 0; i_ < 64; i_ += 4) {                       \
      ac0 = fmaf(read_lane(w, i_ + 0), p[i_ + 0], ac0);        \
      ac1 = fmaf(read_lane(w, i_ + 1), p[i_ + 1], ac1);        \
      ac2 = fmaf(read_lane(w, i_ + 2), p[i_ + 2], ac2);        \
      ac3 = fmaf(read_lane(w, i_ + 3), p[i_ + 3], ac3);        \
    }                                                          \
    float y_ = (ac0 + ac1) + (ac2 + ac3);                      \
    w = y_ * e_;                                               \
    M += (mv);                                                 \
  }

  // steps 1..3
  {
    float m1 = wave_max(Av.y), m2 = wave_max(Av.z), m3 = wave_max(Av.w);
    STEP(Av.y, m1); STEP(Av.z, m2); STEP(Av.w, m3);
    float s = wave_sum(w);
    w *= (1.0f / s);
    M += __logf(s);
  }

  // groups of 4 steps: g covers t = 4g..4g+3, g = 1..511
  for (int g = 1; g < 512; ++g) {
    float4 Dv;
    if (g + 2 < 512) Dv = *reinterpret_cast<const float4*>(lbj + 4 * (g + 2));
    else             Dv = make_float4(0.f, 0.f, 0.f, 0.f);

    float n0 = wave_max(Bv.x), n1 = wave_max(Bv.y);
    float n2 = wave_max(Bv.z), n3 = wave_max(Bv.w);
    STEP(Bv.x, n0);
    STEP(Bv.y, n1);
    STEP(Bv.z, n2);
    STEP(Bv.w, n3);

    // exact renorm (absorbed into M; keeps w in normal fp32 range)
    float s = wave_sum(w);
    w *= (1.0f / s);
    M += __logf(s);

    Bv = Cv; Cv = Dv;
  }
#undef STEP

  // logsumexp_j alpha_T[j] = M + log(sum_j w[j])
  float S = wave_sum(w);
  if (j == 0) part[b] = M + __logf(S);
}

// ---------------- final deterministic sum ----------------
__global__ void final_kernel(const float* __restrict__ part, float* __restrict__ out) {
  float v = part[threadIdx.x];
  float s = wave_sum(v);
  if (threadIdx.x == 0) out[0] = s;
}

extern "C" void kernel_launch(void* const* d_in, const int* in_sizes, int n_in,
                              void* d_out, int out_size, void* d_ws, size_t ws_size,
                              hipStream_t stream) {
  const float* X        = (const float*)d_in[0];
  const float* trans    = (const float*)d_in[1];
  const float* priors   = (const float*)d_in[2];
  const float* means    = (const float*)d_in[3];
  const float* log_vars = (const float*)d_in[4];
  float* ws  = (float*)d_ws;
  float* out = (float*)d_out;

  hipLaunchKernelGGL(setup_kernel, dim3(1), dim3(256), 0, stream,
                     trans, priors, means, log_vars, ws);
  hipLaunchKernelGGL(emis_kernel, dim3(2048), dim3(256), 0, stream,
                     X, ws, ws + LOGB_OFF);
  hipLaunchKernelGGL(forward_kernel, dim3(64), dim3(64), 0, stream,
                     ws, ws + PART_OFF);
  hipLaunchKernelGGL(final_kernel, dim3(1), dim3(64), 0, stream,
                     ws + PART_OFF, out);
}

// Round 4
// 795.727 us; speedup vs baseline: 1.5698x; 1.4958x over previous
//
#include <hip/hip_runtime.h>

// HMM forward: B=64, T=2048, N=64, D=128
// ws layout (float offsets):
//   Pt      @ 0      (64*64)     TRANSPOSED transition probs: Pt[j][i] = P[i][j]
//   Wc      @ 4096   (256*64)    k<128: -0.5*inv_var[d][n] ; k>=128: mean*inv_var[d][n]   ([k][n])
//   cn      @ 20480  (64)        -0.5*(t3 + D*log2pi)
//   log_pi  @ 20544  (64)
//   part    @ 20608  (64)        per-batch final logsumexp
//   logb    @ 20736  (64*64*2048)  emission logprobs, TRANSPOSED: [b][n][t]
// total ~33.6 MB

constexpr int PT_OFF   = 0;
constexpr int WC_OFF   = 4096;
constexpr int CN_OFF   = 20480;
constexpr int LPI_OFF  = 20544;
constexpr int PART_OFF = 20608;
constexpr int LOGB_OFF = 20736;

__device__ inline float wave_max(float v) {
  #pragma unroll
  for (int off = 1; off < 64; off <<= 1) v = fmaxf(v, __shfl_xor(v, off));
  return v;
}
__device__ inline float wave_sum(float v) {
  #pragma unroll
  for (int off = 1; off < 64; off <<= 1) v += __shfl_xor(v, off);
  return v;
}
__device__ inline float read_lane(float v, int l) {
  return __uint_as_float(__builtin_amdgcn_readlane(__float_as_uint(v), l));
}

// ---------------- setup: Pt, log_pi, Wc, cn ----------------
__global__ void setup_kernel(const float* __restrict__ trans,
                             const float* __restrict__ priors,
                             const float* __restrict__ means,
                             const float* __restrict__ log_vars,
                             float* __restrict__ ws) {
  float* Pt  = ws + PT_OFF;
  float* Wc  = ws + WC_OFF;
  float* cn  = ws + CN_OFF;
  float* lpi = ws + LPI_OFF;
  int tid = threadIdx.x, lane = tid & 63, w = tid >> 6;

  // log_softmax over rows of transition -> Pt[col][row] = exp(log_A[row][col])
  for (int r = 0; r < 16; ++r) {
    int i = w * 16 + r;                       // row
    float x = trans[i * 64 + lane];           // col = lane
    float m = wave_max(x);
    float s = wave_sum(__expf(x - m));
    float lse = m + __logf(s);
    Pt[lane * 64 + i] = __expf(x - lse);      // transposed store
  }
  if (w == 0) {
    float x = priors[lane];
    float m = wave_max(x);
    float s = wave_sum(__expf(x - m));
    lpi[lane] = x - (m + __logf(s));
  }
  // combined GEMM weights, [k][n] layout (n fastest)
  for (int idx = tid; idx < 16384; idx += 256) {
    int k = idx >> 6, n = idx & 63;
    int d = (k < 128) ? k : (k - 128);
    float iv = __expf(-log_vars[n * 128 + d]);
    Wc[idx] = (k < 128) ? (-0.5f * iv) : (means[n * 128 + d] * iv);
  }
  // cn[n] = -0.5*(sum_d (mu^2*iv + lv) + D*log(2pi))
  if (tid < 64) {
    int n = tid;
    float s = 0.f;
    for (int d = 0; d < 128; ++d) {
      float lv = log_vars[n * 128 + d];
      float mu = means[n * 128 + d];
      s += mu * mu * __expf(-lv) + lv;
    }
    cn[n] = -0.5f * (s + 128.0f * 1.8378770664093453f);
  }
}

// ---------------- emissions: log_b = A @ Wc + cn, stored [b][n][t] ----------------
__global__ __launch_bounds__(256) void emis_kernel(const float* __restrict__ X,
                                                   const float* __restrict__ ws,
                                                   float* __restrict__ logb) {
  const float* Wc = ws + WC_OFF;
  const float* cn = ws + CN_OFF;
  __shared__ float As[128 * 64];
  __shared__ float Ws[128 * 64];
  int tid = threadIdx.x;
  int r0 = blockIdx.x * 64;

  // stage X tile
  #pragma unroll
  for (int c = 0; c < 8; ++c) {
    int flat = c * 1024 + tid * 4;
    int row = flat >> 7, d = flat & 127;
    float4 xv = *reinterpret_cast<const float4*>(&X[(size_t)(r0 + row) * 128 + d]);
    float xs[4] = {xv.x, xv.y, xv.z, xv.w};
    #pragma unroll
    for (int i = 0; i < 4; ++i) As[(d + i) * 64 + row] = xs[i];
  }
  // stage W half 0 (-0.5*inv_var)
  #pragma unroll
  for (int c = 0; c < 8; ++c) {
    int flat = c * 1024 + tid * 4;
    *reinterpret_cast<float4*>(&Ws[flat]) = *reinterpret_cast<const float4*>(&Wc[flat]);
  }
  __syncthreads();

  int tt = tid & 15, tn = tid >> 4;   // t-row-group (fast), n-group
  float acc[4][4] = {};               // [t-offset][n-offset]

  // phase 0: x^2 terms
  #pragma unroll 4
  for (int d = 0; d < 128; ++d) {
    float4 a4 = *reinterpret_cast<const float4*>(&As[d * 64 + tt * 4]);
    float4 w4 = *reinterpret_cast<const float4*>(&Ws[d * 64 + tn * 4]);
    float av[4] = {a4.x * a4.x, a4.y * a4.y, a4.z * a4.z, a4.w * a4.w};
    float wv[4] = {w4.x, w4.y, w4.z, w4.w};
    #pragma unroll
    for (int i = 0; i < 4; ++i)
      #pragma unroll
      for (int j = 0; j < 4; ++j) acc[i][j] = fmaf(av[i], wv[j], acc[i][j]);
  }
  __syncthreads();
  // stage W half 1 (mean*inv_var)
  #pragma unroll
  for (int c = 0; c < 8; ++c) {
    int flat = c * 1024 + tid * 4;
    *reinterpret_cast<float4*>(&Ws[flat]) = *reinterpret_cast<const float4*>(&Wc[8192 + flat]);
  }
  __syncthreads();
  // phase 1: x terms
  #pragma unroll 4
  for (int d = 0; d < 128; ++d) {
    float4 a4 = *reinterpret_cast<const float4*>(&As[d * 64 + tt * 4]);
    float4 w4 = *reinterpret_cast<const float4*>(&Ws[d * 64 + tn * 4]);
    float av[4] = {a4.x, a4.y, a4.z, a4.w};
    float wv[4] = {w4.x, w4.y, w4.z, w4.w};
    #pragma unroll
    for (int i = 0; i < 4; ++i)
      #pragma unroll
      for (int j = 0; j < 4; ++j) acc[i][j] = fmaf(av[i], wv[j], acc[i][j]);
  }

  float4 c4 = *reinterpret_cast<const float4*>(&cn[tn * 4]);
  float cv[4] = {c4.x, c4.y, c4.z, c4.w};
  int b_idx = r0 >> 11;
  int tbase = (r0 & 2047) + tt * 4;
  #pragma unroll
  for (int jj = 0; jj < 4; ++jj) {
    int n = tn * 4 + jj;
    float4 o;
    o.x = acc[0][jj] + cv[jj];
    o.y = acc[1][jj] + cv[jj];
    o.z = acc[2][jj] + cv[jj];
    o.w = acc[3][jj] + cv[jj];
    *reinterpret_cast<float4*>(&logb[(size_t)b_idx * 131072 + (size_t)n * 2048 + tbase]) = o;
  }
}

// ---------------- forward recursion (single wave per batch) ----------------
// Prob-space recursion, invariant alpha_t[j] = M + log(w[j]).
// Per step:  y[j] = sum_i w[i]*P[i][j]   (64 readlane + 64 fmac, no LDS/barrier)
//            w'[j] = y[j] * exp(lb_t[j] - m_t);  M += m_t   (m_t data-only, off-chain)
// P column j lives in 16 NAMED float4 registers (q0..q15) loaded from the
// transposed Pt — no indexed array, so the allocator cannot demote it.
// __launch_bounds__(64,1) lifts the default-occupancy VGPR cap (round-3 spill:
// VGPR_Count=68 < 64-element column -> scratch reloads dominated the chain).
// Renorm every 8 steps: S' in [1e-15, 1.15]*S bounds — no over/underflow ever.
__global__ __launch_bounds__(64, 1) void forward_kernel(const float* __restrict__ ws,
                                                        float* __restrict__ part) {
  const float* Pt   = ws + PT_OFF;
  const float* lpi  = ws + LPI_OFF;
  const float* logb = ws + LOGB_OFF;

  int b = blockIdx.x;
  int j = threadIdx.x;            // one wave: lane = state j

  // P column j -> 16 named float4 registers
  const float* Ptj = Pt + j * 64;
#define QLOAD(k) float4 q##k = *reinterpret_cast<const float4*>(Ptj + 4 * k);
  QLOAD(0)  QLOAD(1)  QLOAD(2)  QLOAD(3)
  QLOAD(4)  QLOAD(5)  QLOAD(6)  QLOAD(7)
  QLOAD(8)  QLOAD(9)  QLOAD(10) QLOAD(11)
  QLOAD(12) QLOAD(13) QLOAD(14) QLOAD(15)
#undef QLOAD

  const float* lbj = logb + (size_t)b * 131072 + (size_t)j * 2048;

  float4 Av = *reinterpret_cast<const float4*>(lbj + 0);   // t 0..3
  float4 Bv = *reinterpret_cast<const float4*>(lbj + 4);   // t 4..7
  float4 Cv = *reinterpret_cast<const float4*>(lbj + 8);   // t 8..11

  float a0 = lpi[j] + Av.x;
  float M  = wave_max(a0);
  float w  = __expf(a0 - M);

#define QF(k)                                            \
    ac0 = fmaf(read_lane(w, 4 * k + 0), q##k.x, ac0);    \
    ac1 = fmaf(read_lane(w, 4 * k + 1), q##k.y, ac1);    \
    ac2 = fmaf(read_lane(w, 4 * k + 2), q##k.z, ac2);    \
    ac3 = fmaf(read_lane(w, 4 * k + 3), q##k.w, ac3);

#define STEP(lbv, mv) {                                  \
    float e_ = __expf((lbv) - (mv));                     \
    float ac0 = 0.f, ac1 = 0.f, ac2 = 0.f, ac3 = 0.f;    \
    QF(0)  QF(1)  QF(2)  QF(3)                           \
    QF(4)  QF(5)  QF(6)  QF(7)                           \
    QF(8)  QF(9)  QF(10) QF(11)                          \
    QF(12) QF(13) QF(14) QF(15)                          \
    float y_ = (ac0 + ac1) + (ac2 + ac3);                \
    w = y_ * e_;                                         \
    M += (mv);                                           \
  }

  // steps 1..3, then exact renorm (S = 1 entering the group loop)
  {
    float m1 = wave_max(Av.y), m2 = wave_max(Av.z), m3 = wave_max(Av.w);
    STEP(Av.y, m1); STEP(Av.z, m2); STEP(Av.w, m3);
    float s = wave_sum(w);
    w *= (1.0f / s);
    M += __logf(s);
  }

  // groups of 4 steps: g covers t = 4g..4g+3, g = 1..511; renorm every 2 groups
  for (int g = 1; g < 512; ++g) {
    float4 Dv;
    if (g + 2 < 512) Dv = *reinterpret_cast<const float4*>(lbj + 4 * (g + 2));
    else             Dv = make_float4(0.f, 0.f, 0.f, 0.f);

    float n0 = wave_max(Bv.x), n1 = wave_max(Bv.y);
    float n2 = wave_max(Bv.z), n3 = wave_max(Bv.w);
    STEP(Bv.x, n0);
    STEP(Bv.y, n1);
    STEP(Bv.z, n2);
    STEP(Bv.w, n3);

    if (g & 1) {                     // exact renorm, absorbed into M
      float s = wave_sum(w);
      w *= (1.0f / s);
      M += __logf(s);
    }

    Bv = Cv; Cv = Dv;
  }
#undef STEP
#undef QF

  // logsumexp_j alpha_T[j] = M + log(sum_j w[j])
  float S = wave_sum(w);
  if (j == 0) part[b] = M + __logf(S);
}

// ---------------- final deterministic sum ----------------
__global__ void final_kernel(const float* __restrict__ part, float* __restrict__ out) {
  float v = part[threadIdx.x];
  float s = wave_sum(v);
  if (threadIdx.x == 0) out[0] = s;
}

extern "C" void kernel_launch(void* const* d_in, const int* in_sizes, int n_in,
                              void* d_out, int out_size, void* d_ws, size_t ws_size,
                              hipStream_t stream) {
  const float* X        = (const float*)d_in[0];
  const float* trans    = (const float*)d_in[1];
  const float* priors   = (const float*)d_in[2];
  const float* means    = (const float*)d_in[3];
  const float* log_vars = (const float*)d_in[4];
  float* ws  = (float*)d_ws;
  float* out = (float*)d_out;

  hipLaunchKernelGGL(setup_kernel, dim3(1), dim3(256), 0, stream,
                     trans, priors, means, log_vars, ws);
  hipLaunchKernelGGL(emis_kernel, dim3(2048), dim3(256), 0, stream,
                     X, ws, ws + LOGB_OFF);
  hipLaunchKernelGGL(forward_kernel, dim3(64), dim3(64), 0, stream,
                     ws, ws + PART_OFF);
  hipLaunchKernelGGL(final_kernel, dim3(1), dim3(64), 0, stream,
                     ws + PART_OFF, out);
}

// Round 5
// 289.698 us; speedup vs baseline: 4.3118x; 2.7467x over previous
//
#include <hip/hip_runtime.h>

// HMM forward via chunked parallel scan: B=64, T=2048, N=64, D=128
//
// Math: alpha_t = diag(e_t) * A^T * alpha_{t-1},  e_t[j] = exp(lb_t[j] - m_t).
// Phase 1: for each (batch, chunk of 64 steps) propagate full 64x64 matrix
//          D <- diag(e_t) (A^T D) with bf16 MFMA; renorm by max-entry every 4
//          steps (log absorbed). 2048 independent wave-jobs.
// Phase 2: per batch, fold the 32 chunk matrices sequentially (32 matvecs).
//
// ws layout (float units):
//   ATF  @ 0        2048    A^T MFMA A-fragments, pre-arranged per (frag,lane)
//   PI   @ 2048     64      exp(log_softmax(priors))
//   CN   @ 2112     64      -0.5*(t3 + D*log2pi)
//   WC   @ 2176     16384   emission GEMM weights [k][n]
//   MV   @ 18560    131072  m_t per (b,t)  (row max of lb)
//   PART @ 149632   64      per-batch final logsumexp
//   GLS  @ 149696   2048    per (b,chunk) log-scale from phase-1 renorms
//   E    @ 151744   4194304 (= 8388608 bf16)  e values [b][t][n], bf16
//   G    @ 4346048  4194304 (= 8388608 bf16)  chunk matrices G^T [b*32+c][i][j]
// total 8540352 floats = 34.2 MB

constexpr int ATF_OFF  = 0;
constexpr int PI_OFF   = 2048;
constexpr int CN_OFF   = 2112;
constexpr int WC_OFF   = 2176;
constexpr int MV_OFF   = 18560;
constexpr int PART_OFF = 149632;
constexpr int GLS_OFF  = 149696;
constexpr int E_OFF    = 151744;
constexpr int G_OFF    = 4346048;

typedef __attribute__((ext_vector_type(8))) short bf16x8;
typedef __attribute__((ext_vector_type(4))) float f32x4;

__device__ inline float wave_max(float v) {
  #pragma unroll
  for (int off = 1; off < 64; off <<= 1) v = fmaxf(v, __shfl_xor(v, off));
  return v;
}
__device__ inline float wave_sum(float v) {
  #pragma unroll
  for (int off = 1; off < 64; off <<= 1) v += __shfl_xor(v, off);
  return v;
}
__device__ inline float read_lane(float v, int l) {
  return __uint_as_float(__builtin_amdgcn_readlane(__float_as_uint(v), l));
}
// manual round-to-nearest-even f32 -> bf16 (no intrinsic-ordering risk)
__device__ inline unsigned f2bf(float f) {
  unsigned u = __float_as_uint(f);
  u += 0x7FFFu + ((u >> 16) & 1u);
  return u >> 16;
}
__device__ inline float bf2f(unsigned lo16) { return __uint_as_float(lo16 << 16); }

// ---------------- setup: P (log_softmax), AT-frags, pi, Wc, cn ----------------
__global__ void setup_kernel(const float* __restrict__ trans,
                             const float* __restrict__ priors,
                             const float* __restrict__ means,
                             const float* __restrict__ log_vars,
                             float* __restrict__ ws) {
  __shared__ float Psh[64 * 64];
  int tid = threadIdx.x, lane = tid & 63, w = tid >> 6;

  // P[i][j] = exp(log_softmax(trans, rows))
  for (int r = 0; r < 16; ++r) {
    int i = w * 16 + r;
    float x = trans[i * 64 + lane];
    float m = wave_max(x);
    float s = wave_sum(__expf(x - m));
    Psh[i * 64 + lane] = __expf(x - (m + __logf(s)));
  }
  if (w == 0) {
    float x = priors[lane];
    float m = wave_max(x);
    float s = wave_sum(__expf(x - m));
    ws[PI_OFF + lane] = __expf(x - (m + __logf(s)));
  }
  // emission GEMM weights [k][n]
  for (int idx = tid; idx < 16384; idx += 256) {
    int k = idx >> 6, n = idx & 63;
    int d = (k < 128) ? k : (k - 128);
    float iv = __expf(-log_vars[n * 128 + d]);
    ws[WC_OFF + idx] = (k < 128) ? (-0.5f * iv) : (means[n * 128 + d] * iv);
  }
  if (tid < 64) {
    int n = tid;
    float s = 0.f;
    for (int d = 0; d < 128; ++d) {
      float lv = log_vars[n * 128 + d];
      float mu = means[n * 128 + d];
      s += mu * mu * __expf(-lv) + lv;
    }
    ws[CN_OFF + n] = -0.5f * (s + 128.0f * 1.8378770664093453f);
  }
  __syncthreads();
  // A-operand fragments of A^T for mfma_f32_16x16x32_bf16:
  // frag = tM*2 + s ; lane l holds A^T[m=(l&15)+16tM][k=8*(l>>4)+r+32s], r=0..7
  // A^T[m=j][k=i] = P[i][j]. Packed bf16 pairs -> 4 u32 per (frag,lane).
  for (int idx = tid; idx < 512; idx += 256) {
    int frag = idx >> 6, l = idx & 63;
    int tM = frag >> 1, s = frag & 1;
    int m = (l & 15) + 16 * tM;
    int kb = 8 * (l >> 4) + 32 * s;
    unsigned u[4];
    #pragma unroll
    for (int p = 0; p < 4; ++p) {
      unsigned a = f2bf(Psh[(kb + 2 * p) * 64 + m]);
      unsigned b = f2bf(Psh[(kb + 2 * p + 1) * 64 + m]);
      u[p] = a | (b << 16);
    }
    *reinterpret_cast<uint4*>(&ws[ATF_OFF + idx * 4]) = make_uint4(u[0], u[1], u[2], u[3]);
  }
}

// ---------------- emissions: lb tile GEMM + fused row-max/exp -> E (bf16), MV ----------------
__global__ __launch_bounds__(256) void emis_kernel(const float* __restrict__ X,
                                                   float* __restrict__ ws) {
  const float* Wc = ws + WC_OFF;
  const float* cn = ws + CN_OFF;
  __shared__ float As[128 * 64];
  __shared__ float Ws[128 * 64];
  int tid = threadIdx.x;
  int r0 = blockIdx.x * 64;

  // stage X tile, [d][row]
  #pragma unroll
  for (int c = 0; c < 8; ++c) {
    int flat = c * 1024 + tid * 4;
    int row = flat >> 7, d = flat & 127;
    float4 xv = *reinterpret_cast<const float4*>(&X[(size_t)(r0 + row) * 128 + d]);
    float xs[4] = {xv.x, xv.y, xv.z, xv.w};
    #pragma unroll
    for (int i = 0; i < 4; ++i) As[(d + i) * 64 + row] = xs[i];
  }
  // stage W half 0 (-0.5*inv_var)
  #pragma unroll
  for (int c = 0; c < 8; ++c) {
    int flat = c * 1024 + tid * 4;
    *reinterpret_cast<float4*>(&Ws[flat]) = *reinterpret_cast<const float4*>(&Wc[flat]);
  }
  __syncthreads();

  int tr = tid & 15, tc = tid >> 4;   // n-group, row-group
  float acc[4][4] = {};               // [row-off][n-off]

  #pragma unroll 4
  for (int d = 0; d < 128; ++d) {     // x^2 terms
    float4 a4 = *reinterpret_cast<const float4*>(&As[d * 64 + tc * 4]);
    float4 w4 = *reinterpret_cast<const float4*>(&Ws[d * 64 + tr * 4]);
    float av[4] = {a4.x * a4.x, a4.y * a4.y, a4.z * a4.z, a4.w * a4.w};
    float wv[4] = {w4.x, w4.y, w4.z, w4.w};
    #pragma unroll
    for (int i = 0; i < 4; ++i)
      #pragma unroll
      for (int j = 0; j < 4; ++j) acc[i][j] = fmaf(av[i], wv[j], acc[i][j]);
  }
  __syncthreads();
  #pragma unroll
  for (int c = 0; c < 8; ++c) {       // stage W half 1 (mean*inv_var)
    int flat = c * 1024 + tid * 4;
    *reinterpret_cast<float4*>(&Ws[flat]) = *reinterpret_cast<const float4*>(&Wc[8192 + flat]);
  }
  __syncthreads();
  #pragma unroll 4
  for (int d = 0; d < 128; ++d) {     // x terms
    float4 a4 = *reinterpret_cast<const float4*>(&As[d * 64 + tc * 4]);
    float4 w4 = *reinterpret_cast<const float4*>(&Ws[d * 64 + tr * 4]);
    float av[4] = {a4.x, a4.y, a4.z, a4.w};
    float wv[4] = {w4.x, w4.y, w4.z, w4.w};
    #pragma unroll
    for (int i = 0; i < 4; ++i)
      #pragma unroll
      for (int j = 0; j < 4; ++j) acc[i][j] = fmaf(av[i], wv[j], acc[i][j]);
  }

  float4 c4 = *reinterpret_cast<const float4*>(&cn[tr * 4]);
  float cv[4] = {c4.x, c4.y, c4.z, c4.w};

  // stash lb tile to LDS (reuse As space), then fused row-max / exp / bf16 E
  __syncthreads();
  float* Cs = As;
  #pragma unroll
  for (int i = 0; i < 4; ++i)
    #pragma unroll
    for (int j = 0; j < 4; ++j)
      Cs[(tc * 4 + i) * 64 + tr * 4 + j] = acc[i][j] + cv[j];
  __syncthreads();

  {
    int wv = tid >> 6, ln = tid & 63;
    unsigned short* Ep = reinterpret_cast<unsigned short*>(&ws[E_OFF]);
    float* MVp = &ws[MV_OFF];
    for (int rr = 0; rr < 16; ++rr) {
      int row = wv * 16 + rr;
      float v = Cs[row * 64 + ln];
      float m = wave_max(v);
      Ep[(size_t)(r0 + row) * 64 + ln] = (unsigned short)f2bf(__expf(v - m));
      if (ln == 0) MVp[r0 + row] = m;
    }
  }
}

// ---------------- phase 1: chunk scan, one wave per (batch, chunk) ----------------
// D (64x64) lives in LDS as Dimg[n=start-state][k=state], bf16, rows XOR-swizzled
// (byte ^= (n&7)<<4) for bank spread. Per step:
//   B-frags <- Dimg (8x ds_read_b128); C = A^T x D (32 MFMA, static A-frags);
//   scale rows m by e_t[m] (* pending 1/renorm); every 4 steps log max-renorm;
//   pack bf16, write back (16x ds_write_b64).
__global__ __launch_bounds__(64, 2) void fwd1_scan(float* __restrict__ ws) {
  __shared__ __align__(16) unsigned char Dimg[8192];
  const int lane = threadIdx.x;
  const int g = lane >> 4, c15 = lane & 15;
  const int job = blockIdx.x, b = job >> 5, cch = job & 31;

  // static A^T fragments
  bf16x8 at[8];
  #pragma unroll
  for (int f = 0; f < 8; ++f)
    at[f] = *reinterpret_cast<const bf16x8*>(&ws[ATF_OFF + (f * 64 + lane) * 4]);

  // identity init: row n = lane
  {
    int n = lane;
    unsigned sw = (unsigned)((n & 7) << 4);
    #pragma unroll
    for (int q = 0; q < 8; ++q)
      *reinterpret_cast<uint4*>(&Dimg[(unsigned)(n * 128 + 16 * q) ^ sw]) = make_uint4(0, 0, 0, 0);
    unsigned addr = ((unsigned)(n * 128 + 4 * (n >> 1))) ^ sw;
    *reinterpret_cast<unsigned*>(&Dimg[addr]) = (n & 1) ? 0x3F800000u : 0x00003F80u;
  }
  __syncthreads();

  const int tstart = 1 + cch * 64;
  const int len = (cch == 31) ? 63 : 64;
  const unsigned short* Eb =
      reinterpret_cast<const unsigned short*>(&ws[E_OFF]) + ((size_t)b * 2048 + tstart) * 64;

  uint2 eF[4];
  #pragma unroll
  for (int tM = 0; tM < 4; ++tM)
    eF[tM] = *reinterpret_cast<const uint2*>(Eb + 16 * tM + 4 * g);

  float Ls = 0.f, rescale = 1.f;

  for (int step = 0; step < len; ++step) {
    uint2 eC[4];
    #pragma unroll
    for (int tM = 0; tM < 4; ++tM) eC[tM] = eF[tM];
    if (step + 1 < len) {
      #pragma unroll
      for (int tM = 0; tM < 4; ++tM)
        eF[tM] = *reinterpret_cast<const uint2*>(Eb + (size_t)(step + 1) * 64 + 16 * tM + 4 * g);
    }

    // B-frags: lane holds D[k = 8g+{0..7}+32s][n = c15+16tN]
    bf16x8 bfr[8];
    #pragma unroll
    for (int tN = 0; tN < 4; ++tN) {
      int n = c15 + 16 * tN;
      unsigned sw = (unsigned)((n & 7) << 4);
      unsigned base = (unsigned)(n * 128 + 16 * g);
      bfr[tN * 2 + 0] = *reinterpret_cast<const bf16x8*>(&Dimg[(base + 0) ^ sw]);
      bfr[tN * 2 + 1] = *reinterpret_cast<const bf16x8*>(&Dimg[(base + 64) ^ sw]);
    }

    // C = A^T * D
    f32x4 Cf[4][4];
    #pragma unroll
    for (int tM = 0; tM < 4; ++tM)
      #pragma unroll
      for (int tN = 0; tN < 4; ++tN) {
        f32x4 z = {0.f, 0.f, 0.f, 0.f};
        z = __builtin_amdgcn_mfma_f32_16x16x32_bf16(at[tM * 2 + 0], bfr[tN * 2 + 0], z, 0, 0, 0);
        Cf[tM][tN] = __builtin_amdgcn_mfma_f32_16x16x32_bf16(at[tM * 2 + 1], bfr[tN * 2 + 1], z, 0, 0, 0);
      }

    // row scale by e_t[m] (m = 16tM + 4g + r), with pending renorm folded in
    float ef[4][4];
    #pragma unroll
    for (int tM = 0; tM < 4; ++tM) {
      ef[tM][0] = __uint_as_float(eC[tM].x << 16) * rescale;
      ef[tM][1] = __uint_as_float(eC[tM].x & 0xFFFF0000u) * rescale;
      ef[tM][2] = __uint_as_float(eC[tM].y << 16) * rescale;
      ef[tM][3] = __uint_as_float(eC[tM].y & 0xFFFF0000u) * rescale;
    }
    #pragma unroll
    for (int tM = 0; tM < 4; ++tM)
      #pragma unroll
      for (int tN = 0; tN < 4; ++tN)
        #pragma unroll
        for (int r = 0; r < 4; ++r) Cf[tM][tN][r] *= ef[tM][r];

    // max-entry renorm every 4 steps (deferred: applied via next step's e)
    if ((step & 3) == 3 && step != len - 1) {
      float mx = 0.f;
      #pragma unroll
      for (int tM = 0; tM < 4; ++tM)
        #pragma unroll
        for (int tN = 0; tN < 4; ++tN) {
          f32x4 v = Cf[tM][tN];
          mx = fmaxf(mx, fmaxf(fmaxf(v[0], v[1]), fmaxf(v[2], v[3])));
        }
      mx = wave_max(mx);
      Ls += __logf(mx);
      rescale = 1.0f / mx;
    } else {
      rescale = 1.0f;
    }

    // pack bf16, write D_next (lane writes rows m..m+3 of column n -> contiguous)
    #pragma unroll
    for (int tN = 0; tN < 4; ++tN) {
      int n = c15 + 16 * tN;
      unsigned sw = (unsigned)((n & 7) << 4);
      #pragma unroll
      for (int tM = 0; tM < 4; ++tM) {
        f32x4 v = Cf[tM][tN];
        unsigned w0 = f2bf(v[0]) | (f2bf(v[1]) << 16);
        unsigned w1 = f2bf(v[2]) | (f2bf(v[3]) << 16);
        unsigned addr = ((unsigned)(n * 128 + 32 * tM + 8 * g)) ^ sw;
        *reinterpret_cast<uint2*>(&Dimg[addr]) = make_uint2(w0, w1);
      }
    }
    __syncthreads();
  }

  // store G^T (de-swizzled) + chunk log-scale
  unsigned short* Gb = reinterpret_cast<unsigned short*>(&ws[G_OFF]) + (size_t)job * 4096;
  {
    int n = lane;
    unsigned sw = (unsigned)((n & 7) << 4);
    #pragma unroll
    for (int q = 0; q < 8; ++q) {
      uint4 v = *reinterpret_cast<const uint4*>(&Dimg[(unsigned)(n * 128 + 16 * q) ^ sw]);
      *reinterpret_cast<uint4*>(Gb + n * 64 + q * 8) = v;
    }
  }
  if (lane == 0) ws[GLS_OFF + job] = Ls;
}

// ---------------- phase 2: fold 32 chunk matrices per batch ----------------
__global__ __launch_bounds__(64, 1) void fwd2_combine(float* __restrict__ ws) {
  int b = blockIdx.x, j = threadIdx.x;

  // sum of all m_t for this batch
  float Ms = 0.f;
  for (int k = 0; k < 32; ++k) Ms += ws[MV_OFF + (size_t)b * 2048 + k * 64 + j];
  Ms = wave_sum(Ms);

  const unsigned short* E0 =
      reinterpret_cast<const unsigned short*>(&ws[E_OFF]) + (size_t)b * 2048 * 64;
  float w = ws[PI_OFF + j] * bf2f((unsigned)E0[j]);   // alpha_0 modulo exp(m_0)
  float Lacc = Ms;

  const unsigned short* Gb =
      reinterpret_cast<const unsigned short*>(&ws[G_OFF]) + (size_t)b * 32 * 4096;
  for (int c = 0; c < 32; ++c) {
    float gv[64];
    #pragma unroll
    for (int i = 0; i < 64; ++i)
      gv[i] = bf2f((unsigned)Gb[c * 4096 + i * 64 + j]);   // G^T[i][j] = G[j][i]
    float a0 = 0.f, a1 = 0.f, a2 = 0.f, a3 = 0.f;
    #pragma unroll
    for (int i = 0; i < 64; i += 4) {
      a0 = fmaf(read_lane(w, i + 0), gv[i + 0], a0);
      a1 = fmaf(read_lane(w, i + 1), gv[i + 1], a1);
      a2 = fmaf(read_lane(w, i + 2), gv[i + 2], a2);
      a3 = fmaf(read_lane(w, i + 3), gv[i + 3], a3);
    }
    float y = (a0 + a1) + (a2 + a3);
    float s = wave_sum(y);
    w = y * (1.0f / s);
    Lacc += __logf(s) + ws[GLS_OFF + b * 32 + c];
  }
  float S = wave_sum(w);
  if (j == 0) ws[PART_OFF + b] = Lacc + __logf(S);
}

// ---------------- final deterministic sum ----------------
__global__ void final_kernel(const float* __restrict__ part, float* __restrict__ out) {
  float v = part[threadIdx.x];
  float s = wave_sum(v);
  if (threadIdx.x == 0) out[0] = s;
}

extern "C" void kernel_launch(void* const* d_in, const int* in_sizes, int n_in,
                              void* d_out, int out_size, void* d_ws, size_t ws_size,
                              hipStream_t stream) {
  const float* X        = (const float*)d_in[0];
  const float* trans    = (const float*)d_in[1];
  const float* priors   = (const float*)d_in[2];
  const float* means    = (const float*)d_in[3];
  const float* log_vars = (const float*)d_in[4];
  float* ws  = (float*)d_ws;
  float* out = (float*)d_out;

  hipLaunchKernelGGL(setup_kernel, dim3(1), dim3(256), 0, stream,
                     trans, priors, means, log_vars, ws);
  hipLaunchKernelGGL(emis_kernel, dim3(2048), dim3(256), 0, stream, X, ws);
  hipLaunchKernelGGL(fwd1_scan, dim3(2048), dim3(64), 0, stream, ws);
  hipLaunchKernelGGL(fwd2_combine, dim3(64), dim3(64), 0, stream, ws);
  hipLaunchKernelGGL(final_kernel, dim3(1), dim3(64), 0, stream,
                     ws + PART_OFF, out);
}

// Round 6
// 267.984 us; speedup vs baseline: 4.6612x; 1.0810x over previous
//
#include <hip/hip_runtime.h>

// HMM forward via chunked parallel scan: B=64, T=2048, N=64, D=128
//
// Math: alpha_t = diag(e_t) * A^T * alpha_{t-1},  e_t[j] = exp(lb_t[j] - m_t).
// Phase 1: per (batch, chunk of 64 steps) propagate 64x64 matrix
//          D <- diag(e_t) (A^T D) entirely in REGISTERS using 32x32x16 bf16
//          MFMA; C->B operand relayout via v_permlane32_swap_b32 (no LDS, no
//          barriers); max-entry renorm every 8 steps (log absorbed).
// Phase 2: per batch, fold the 32 chunk matrices sequentially.
//
// ws layout (float units):
//   ATF  @ 0        2048    A^T MFMA A-fragments (32x32x16), per (frag,lane)
//   PI   @ 2048     64      exp(log_softmax(priors))
//   CN   @ 2112     64      -0.5*(t3 + D*log2pi)
//   WC   @ 2176     16384   emission GEMM weights [k][n]
//   MV   @ 18560    131072  m_t per (b,t)  (row max of lb)
//   PART @ 149632   64      per-batch final logsumexp
//   GLS  @ 149696   2048    per (b,chunk) log-scale from phase-1 renorms
//   E    @ 151744   4194304 (= 8388608 bf16)  e values [b][t][n], bf16
//   G    @ 4346048  4194304 (= 8388608 bf16)  chunk matrices [b*32+c][start][new]
// total 8540352 floats = 34.2 MB

constexpr int ATF_OFF  = 0;
constexpr int PI_OFF   = 2048;
constexpr int CN_OFF   = 2112;
constexpr int WC_OFF   = 2176;
constexpr int MV_OFF   = 18560;
constexpr int PART_OFF = 149632;
constexpr int GLS_OFF  = 149696;
constexpr int E_OFF    = 151744;
constexpr int G_OFF    = 4346048;

typedef __attribute__((ext_vector_type(8))) short bf16x8;
typedef __attribute__((ext_vector_type(4))) float f32x4;
typedef __attribute__((ext_vector_type(16))) float f32x16;

union BU { unsigned u[4]; bf16x8 v; };

__device__ inline float wave_max(float v) {
  #pragma unroll
  for (int off = 1; off < 64; off <<= 1) v = fmaxf(v, __shfl_xor(v, off));
  return v;
}
__device__ inline float wave_sum(float v) {
  #pragma unroll
  for (int off = 1; off < 64; off <<= 1) v += __shfl_xor(v, off);
  return v;
}
__device__ inline float read_lane(float v, int l) {
  return __uint_as_float(__builtin_amdgcn_readlane(__float_as_uint(v), l));
}
// manual round-to-nearest-even f32 -> bf16 (host-free setup path)
__device__ inline unsigned f2bf(float f) {
  unsigned u = __float_as_uint(f);
  u += 0x7FFFu + ((u >> 16) & 1u);
  return u >> 16;
}
__device__ inline float bf2f(unsigned lo16) { return __uint_as_float(lo16 << 16); }
// packed f32x2 -> bf16x2 (RNE), single VALU instruction
__device__ inline unsigned cvt_pk(float lo, float hi) {
  unsigned r;
  asm("v_cvt_pk_bf16_f32 %0, %1, %2" : "=v"(r) : "v"(lo), "v"(hi));
  return r;
}

// ---------------- setup: P (log_softmax), 32x32 AT-frags, pi, Wc, cn ----------------
__global__ void setup_kernel(const float* __restrict__ trans,
                             const float* __restrict__ priors,
                             const float* __restrict__ means,
                             const float* __restrict__ log_vars,
                             float* __restrict__ ws) {
  __shared__ float Psh[64 * 64];
  int tid = threadIdx.x, lane = tid & 63, w = tid >> 6;

  // P[i][j] = exp(log_softmax(trans, rows))
  for (int r = 0; r < 16; ++r) {
    int i = w * 16 + r;
    float x = trans[i * 64 + lane];
    float m = wave_max(x);
    float s = wave_sum(__expf(x - m));
    Psh[i * 64 + lane] = __expf(x - (m + __logf(s)));
  }
  if (w == 0) {
    float x = priors[lane];
    float m = wave_max(x);
    float s = wave_sum(__expf(x - m));
    ws[PI_OFF + lane] = __expf(x - (m + __logf(s)));
  }
  // emission GEMM weights [k][n]
  for (int idx = tid; idx < 16384; idx += 256) {
    int k = idx >> 6, n = idx & 63;
    int d = (k < 128) ? k : (k - 128);
    float iv = __expf(-log_vars[n * 128 + d]);
    ws[WC_OFF + idx] = (k < 128) ? (-0.5f * iv) : (means[n * 128 + d] * iv);
  }
  // cn[n], 4-way unrolled so the serial L2-latency loads pipeline
  if (tid < 64) {
    int n = tid;
    float s0 = 0.f, s1 = 0.f, s2 = 0.f, s3 = 0.f;
    for (int d = 0; d < 128; d += 4) {
      float lv0 = log_vars[n * 128 + d + 0], mu0 = means[n * 128 + d + 0];
      float lv1 = log_vars[n * 128 + d + 1], mu1 = means[n * 128 + d + 1];
      float lv2 = log_vars[n * 128 + d + 2], mu2 = means[n * 128 + d + 2];
      float lv3 = log_vars[n * 128 + d + 3], mu3 = means[n * 128 + d + 3];
      s0 += mu0 * mu0 * __expf(-lv0) + lv0;
      s1 += mu1 * mu1 * __expf(-lv1) + lv1;
      s2 += mu2 * mu2 * __expf(-lv2) + lv2;
      s3 += mu3 * mu3 * __expf(-lv3) + lv3;
    }
    ws[CN_OFF + n] = -0.5f * ((s0 + s1) + (s2 + s3) + 128.0f * 1.8378770664093453f);
  }
  __syncthreads();
  // A-operand fragments of A^T for mfma_f32_32x32x16_bf16:
  // frag f = I*4 + Kb ; lane l holds A_op[m=32I+(l&31)][k=16Kb+8*(l>>5)+j], j=0..7
  // A_op[m][k] = P[k][m]. Packed bf16 pairs (j even lo, j odd hi).
  for (int idx = tid; idx < 512; idx += 256) {
    int f = idx >> 6, l = idx & 63;
    int I = f >> 2, Kb = f & 3;
    int m = 32 * I + (l & 31);
    int kb = 16 * Kb + 8 * (l >> 5);
    unsigned u[4];
    #pragma unroll
    for (int p = 0; p < 4; ++p) {
      unsigned a = f2bf(Psh[(kb + 2 * p) * 64 + m]);
      unsigned b = f2bf(Psh[(kb + 2 * p + 1) * 64 + m]);
      u[p] = a | (b << 16);
    }
    *reinterpret_cast<uint4*>(&ws[ATF_OFF + idx * 4]) = make_uint4(u[0], u[1], u[2], u[3]);
  }
}

// ---------------- emissions: lb tile GEMM + fused row-max/exp -> E (bf16), MV ----------------
__global__ __launch_bounds__(256) void emis_kernel(const float* __restrict__ X,
                                                   float* __restrict__ ws) {
  const float* Wc = ws + WC_OFF;
  const float* cn = ws + CN_OFF;
  __shared__ float As[128 * 64];
  __shared__ float Ws[128 * 64];
  int tid = threadIdx.x;
  int r0 = blockIdx.x * 64;

  #pragma unroll
  for (int c = 0; c < 8; ++c) {
    int flat = c * 1024 + tid * 4;
    int row = flat >> 7, d = flat & 127;
    float4 xv = *reinterpret_cast<const float4*>(&X[(size_t)(r0 + row) * 128 + d]);
    float xs[4] = {xv.x, xv.y, xv.z, xv.w};
    #pragma unroll
    for (int i = 0; i < 4; ++i) As[(d + i) * 64 + row] = xs[i];
  }
  #pragma unroll
  for (int c = 0; c < 8; ++c) {
    int flat = c * 1024 + tid * 4;
    *reinterpret_cast<float4*>(&Ws[flat]) = *reinterpret_cast<const float4*>(&Wc[flat]);
  }
  __syncthreads();

  int tr = tid & 15, tc = tid >> 4;
  float acc[4][4] = {};

  #pragma unroll 4
  for (int d = 0; d < 128; ++d) {
    float4 a4 = *reinterpret_cast<const float4*>(&As[d * 64 + tc * 4]);
    float4 w4 = *reinterpret_cast<const float4*>(&Ws[d * 64 + tr * 4]);
    float av[4] = {a4.x * a4.x, a4.y * a4.y, a4.z * a4.z, a4.w * a4.w};
    float wv[4] = {w4.x, w4.y, w4.z, w4.w};
    #pragma unroll
    for (int i = 0; i < 4; ++i)
      #pragma unroll
      for (int j = 0; j < 4; ++j) acc[i][j] = fmaf(av[i], wv[j], acc[i][j]);
  }
  __syncthreads();
  #pragma unroll
  for (int c = 0; c < 8; ++c) {
    int flat = c * 1024 + tid * 4;
    *reinterpret_cast<float4*>(&Ws[flat]) = *reinterpret_cast<const float4*>(&Wc[8192 + flat]);
  }
  __syncthreads();
  #pragma unroll 4
  for (int d = 0; d < 128; ++d) {
    float4 a4 = *reinterpret_cast<const float4*>(&As[d * 64 + tc * 4]);
    float4 w4 = *reinterpret_cast<const float4*>(&Ws[d * 64 + tr * 4]);
    float av[4] = {a4.x, a4.y, a4.z, a4.w};
    float wv[4] = {w4.x, w4.y, w4.z, w4.w};
    #pragma unroll
    for (int i = 0; i < 4; ++i)
      #pragma unroll
      for (int j = 0; j < 4; ++j) acc[i][j] = fmaf(av[i], wv[j], acc[i][j]);
  }

  float4 c4 = *reinterpret_cast<const float4*>(&cn[tr * 4]);
  float cv[4] = {c4.x, c4.y, c4.z, c4.w};

  __syncthreads();
  float* Cs = As;
  #pragma unroll
  for (int i = 0; i < 4; ++i)
    #pragma unroll
    for (int j = 0; j < 4; ++j)
      Cs[(tc * 4 + i) * 64 + tr * 4 + j] = acc[i][j] + cv[j];
  __syncthreads();

  {
    int wv = tid >> 6, ln = tid & 63;
    unsigned short* Ep = reinterpret_cast<unsigned short*>(&ws[E_OFF]);
    float* MVp = &ws[MV_OFF];
    for (int rr = 0; rr < 16; ++rr) {
      int row = wv * 16 + rr;
      float v = Cs[row * 64 + ln];
      float m = wave_max(v);
      Ep[(size_t)(r0 + row) * 64 + ln] = (unsigned short)f2bf(__expf(v - m));
      if (ln == 0) MVp[r0 + row] = m;
    }
  }
}

// ---------------- phase 1: chunk scan, one wave per (batch, chunk), all-register ----------------
// D as 2x2 tiles of 32x32 (C-layout, m74/m101-verified): tile (I,J), lane (h,il):
//   reg e: row = 32I + (e&3) + 8(e>>2) + 4h, col = 32J + il.
// B-operand build (C -> next-step B): per (Kb,J): pack quads q_e=2(Kb&1),
// q_o=q_e+1 via v_cvt_pk_bf16_f32; one v_permlane32_swap_b32 per packed pair
// delivers B = [Xe',Xe1',Xo',Xo1'] uniformly to both lane halves.
__global__ __launch_bounds__(64, 2) void fwd1_scan(float* __restrict__ ws) {
  const int lane = threadIdx.x;
  const int h = lane >> 5, il = lane & 31;
  const int job = blockIdx.x, b = job >> 5, cch = job & 31;

  // static A^T fragments (I*4+Kb)
  bf16x8 atf[8];
  #pragma unroll
  for (int f = 0; f < 8; ++f)
    atf[f] = *reinterpret_cast<const bf16x8*>(&ws[ATF_OFF + (f * 64 + lane) * 4]);

  // D = identity
  f32x16 c00, c01, c10, c11;
  #pragma unroll
  for (int e = 0; e < 16; ++e) {
    float v = (((e & 3) + 8 * (e >> 2) + 4 * h) == il) ? 1.0f : 0.0f;
    c00[e] = v; c11[e] = v; c01[e] = 0.0f; c10[e] = 0.0f;
  }

  const int tstart = 1 + cch * 64;
  const int len = (cch == 31) ? 63 : 64;
  const char* Eb = (const char*)(ws + E_OFF) + ((size_t)b * 2048 + tstart) * 128;

  // e prefetch: 8 uint2 (chunks of 4 bf16 at m0 = 32I+8q+4h), f = 4I+q
  uint2 eF[8];
  #pragma unroll
  for (int f = 0; f < 8; ++f)
    eF[f] = *(const uint2*)(Eb + 64 * (f >> 2) + 16 * (f & 3) + 8 * h);

  float Ls = 0.0f;

#define BUILD_B(dst, Ct, p) {                                        \
    unsigned xe0 = cvt_pk((Ct)[8*(p)+0], (Ct)[8*(p)+1]);             \
    unsigned xe1 = cvt_pk((Ct)[8*(p)+2], (Ct)[8*(p)+3]);             \
    unsigned xo0 = cvt_pk((Ct)[8*(p)+4], (Ct)[8*(p)+5]);             \
    unsigned xo1 = cvt_pk((Ct)[8*(p)+6], (Ct)[8*(p)+7]);             \
    asm("v_permlane32_swap_b32 %0, %1" : "+v"(xe0), "+v"(xo0));      \
    asm("v_permlane32_swap_b32 %0, %1" : "+v"(xe1), "+v"(xo1));      \
    BU bu_; bu_.u[0] = xe0; bu_.u[1] = xe1; bu_.u[2] = xo0; bu_.u[3] = xo1; \
    dst = bu_.v; }

  for (int step = 0; step < len; ++step) {
    uint2 eC[8];
    #pragma unroll
    for (int f = 0; f < 8; ++f) eC[f] = eF[f];
    if (step + 1 < len) {
      const char* Er = Eb + (size_t)(step + 1) * 128;
      #pragma unroll
      for (int f = 0; f < 8; ++f)
        eF[f] = *(const uint2*)(Er + 64 * (f >> 2) + 16 * (f & 3) + 8 * h);
    }

    // B-frags from current D (before overwrite)
    bf16x8 b00, b10, b20, b30, b01, b11, b21, b31;   // bKb_J
    BUILD_B(b00, c00, 0) BUILD_B(b10, c00, 1)
    BUILD_B(b20, c10, 0) BUILD_B(b30, c10, 1)
    BUILD_B(b01, c01, 0) BUILD_B(b11, c01, 1)
    BUILD_B(b21, c11, 0) BUILD_B(b31, c11, 1)

    // unpack e (row scale) : ef[I][4q+r] = e[32I+8q+4h+r]
    float ef0[16], ef1[16];
    #pragma unroll
    for (int q = 0; q < 4; ++q) {
      uint2 u0 = eC[q], u1 = eC[4 + q];
      ef0[4*q+0] = __uint_as_float(u0.x << 16);
      ef0[4*q+1] = __uint_as_float(u0.x & 0xFFFF0000u);
      ef0[4*q+2] = __uint_as_float(u0.y << 16);
      ef0[4*q+3] = __uint_as_float(u0.y & 0xFFFF0000u);
      ef1[4*q+0] = __uint_as_float(u1.x << 16);
      ef1[4*q+1] = __uint_as_float(u1.x & 0xFFFF0000u);
      ef1[4*q+2] = __uint_as_float(u1.y << 16);
      ef1[4*q+3] = __uint_as_float(u1.y & 0xFFFF0000u);
    }

    // C(I,J) = diag(e) * sum_Kb A(I,Kb) x B(Kb,J)
    {
      f32x16 a;
      #pragma unroll
      for (int z = 0; z < 16; ++z) a[z] = 0.f;
      a = __builtin_amdgcn_mfma_f32_32x32x16_bf16(atf[0], b00, a, 0, 0, 0);
      a = __builtin_amdgcn_mfma_f32_32x32x16_bf16(atf[1], b10, a, 0, 0, 0);
      a = __builtin_amdgcn_mfma_f32_32x32x16_bf16(atf[2], b20, a, 0, 0, 0);
      a = __builtin_amdgcn_mfma_f32_32x32x16_bf16(atf[3], b30, a, 0, 0, 0);
      #pragma unroll
      for (int z = 0; z < 16; ++z) c00[z] = a[z] * ef0[z];
    }
    {
      f32x16 a;
      #pragma unroll
      for (int z = 0; z < 16; ++z) a[z] = 0.f;
      a = __builtin_amdgcn_mfma_f32_32x32x16_bf16(atf[0], b01, a, 0, 0, 0);
      a = __builtin_amdgcn_mfma_f32_32x32x16_bf16(atf[1], b11, a, 0, 0, 0);
      a = __builtin_amdgcn_mfma_f32_32x32x16_bf16(atf[2], b21, a, 0, 0, 0);
      a = __builtin_amdgcn_mfma_f32_32x32x16_bf16(atf[3], b31, a, 0, 0, 0);
      #pragma unroll
      for (int z = 0; z < 16; ++z) c01[z] = a[z] * ef0[z];
    }
    {
      f32x16 a;
      #pragma unroll
      for (int z = 0; z < 16; ++z) a[z] = 0.f;
      a = __builtin_amdgcn_mfma_f32_32x32x16_bf16(atf[4], b00, a, 0, 0, 0);
      a = __builtin_amdgcn_mfma_f32_32x32x16_bf16(atf[5], b10, a, 0, 0, 0);
      a = __builtin_amdgcn_mfma_f32_32x32x16_bf16(atf[6], b20, a, 0, 0, 0);
      a = __builtin_amdgcn_mfma_f32_32x32x16_bf16(atf[7], b30, a, 0, 0, 0);
      #pragma unroll
      for (int z = 0; z < 16; ++z) c10[z] = a[z] * ef1[z];
    }
    {
      f32x16 a;
      #pragma unroll
      for (int z = 0; z < 16; ++z) a[z] = 0.f;
      a = __builtin_amdgcn_mfma_f32_32x32x16_bf16(atf[4], b01, a, 0, 0, 0);
      a = __builtin_amdgcn_mfma_f32_32x32x16_bf16(atf[5], b11, a, 0, 0, 0);
      a = __builtin_amdgcn_mfma_f32_32x32x16_bf16(atf[6], b21, a, 0, 0, 0);
      a = __builtin_amdgcn_mfma_f32_32x32x16_bf16(atf[7], b31, a, 0, 0, 0);
      #pragma unroll
      for (int z = 0; z < 16; ++z) c11[z] = a[z] * ef1[z];
    }

    // max-entry renorm every 8 steps (shrink bound per 8 steps ~3e-15: f32-safe)
    if ((step & 7) == 7) {
      float mx = 0.f;
      #pragma unroll
      for (int z = 0; z < 16; ++z)
        mx = fmaxf(mx, fmaxf(fmaxf(c00[z], c01[z]), fmaxf(c10[z], c11[z])));
      mx = wave_max(mx);
      float inv = 1.0f / mx;
      Ls += __logf(mx);
      #pragma unroll
      for (int z = 0; z < 16; ++z) {
        c00[z] *= inv; c01[z] *= inv; c10[z] *= inv; c11[z] *= inv;
      }
    }
  }
#undef BUILD_B

  // store G[start n][new m] = C[m][n]  (bf16), 16 uint2 stores
  unsigned short* Gb = reinterpret_cast<unsigned short*>(&ws[G_OFF]) + (size_t)job * 4096;
#define STORE_T(Ct, I, J) {                                          \
    _Pragma("unroll")                                                \
    for (int q = 0; q < 4; ++q) {                                    \
      unsigned w0 = cvt_pk((Ct)[4*q+0], (Ct)[4*q+1]);                \
      unsigned w1 = cvt_pk((Ct)[4*q+2], (Ct)[4*q+3]);                \
      *(uint2*)(Gb + (32*(J) + il) * 64 + 32*(I) + 8*q + 4*h) = make_uint2(w0, w1); \
    } }
  STORE_T(c00, 0, 0) STORE_T(c01, 0, 1) STORE_T(c10, 1, 0) STORE_T(c11, 1, 1)
#undef STORE_T
  if (lane == 0) ws[GLS_OFF + job] = Ls;
}

// ---------------- phase 2: fold 32 chunk matrices per batch ----------------
__global__ __launch_bounds__(64, 1) void fwd2_combine(float* __restrict__ ws) {
  int b = blockIdx.x, j = threadIdx.x;

  float Ms = 0.f;
  for (int k = 0; k < 32; ++k) Ms += ws[MV_OFF + (size_t)b * 2048 + k * 64 + j];
  Ms = wave_sum(Ms);

  const unsigned short* E0 =
      reinterpret_cast<const unsigned short*>(&ws[E_OFF]) + (size_t)b * 2048 * 64;
  float w = ws[PI_OFF + j] * bf2f((unsigned)E0[j]);   // alpha_0 modulo exp(m_0)
  float Lacc = Ms;

  const unsigned short* Gb =
      reinterpret_cast<const unsigned short*>(&ws[G_OFF]) + (size_t)b * 32 * 4096;
  for (int c = 0; c < 32; ++c) {
    float gv[64];
    #pragma unroll
    for (int i = 0; i < 64; ++i)
      gv[i] = bf2f((unsigned)Gb[c * 4096 + i * 64 + j]);
    float a0 = 0.f, a1 = 0.f, a2 = 0.f, a3 = 0.f;
    #pragma unroll
    for (int i = 0; i < 64; i += 4) {
      a0 = fmaf(read_lane(w, i + 0), gv[i + 0], a0);
      a1 = fmaf(read_lane(w, i + 1), gv[i + 1], a1);
      a2 = fmaf(read_lane(w, i + 2), gv[i + 2], a2);
      a3 = fmaf(read_lane(w, i + 3), gv[i + 3], a3);
    }
    float y = (a0 + a1) + (a2 + a3);
    float s = wave_sum(y);
    w = y * (1.0f / s);
    Lacc += __logf(s) + ws[GLS_OFF + b * 32 + c];
  }
  float S = wave_sum(w);
  if (j == 0) ws[PART_OFF + b] = Lacc + __logf(S);
}

// ---------------- final deterministic sum ----------------
__global__ void final_kernel(const float* __restrict__ part, float* __restrict__ out) {
  float v = part[threadIdx.x];
  float s = wave_sum(v);
  if (threadIdx.x == 0) out[0] = s;
}

extern "C" void kernel_launch(void* const* d_in, const int* in_sizes, int n_in,
                              void* d_out, int out_size, void* d_ws, size_t ws_size,
                              hipStream_t stream) {
  const float* X        = (const float*)d_in[0];
  const float* trans    = (const float*)d_in[1];
  const float* priors   = (const float*)d_in[2];
  const float* means    = (const float*)d_in[3];
  const float* log_vars = (const float*)d_in[4];
  float* ws  = (float*)d_ws;
  float* out = (float*)d_out;

  hipLaunchKernelGGL(setup_kernel, dim3(1), dim3(256), 0, stream,
                     trans, priors, means, log_vars, ws);
  hipLaunchKernelGGL(emis_kernel, dim3(2048), dim3(256), 0, stream, X, ws);
  hipLaunchKernelGGL(fwd1_scan, dim3(2048), dim3(64), 0, stream, ws);
  hipLaunchKernelGGL(fwd2_combine, dim3(64), dim3(64), 0, stream, ws);
  hipLaunchKernelGGL(final_kernel, dim3(1), dim3(64), 0, stream,
                     ws + PART_OFF, out);
}

// Round 7
// 142.717 us; speedup vs baseline: 8.7524x; 1.8777x over previous
//
#include <hip/hip_runtime.h>

// HMM forward via chunked parallel scan: B=64, T=2048, N=64, D=128
//
// Math: alpha_t = diag(e_t) * A^T * alpha_{t-1},  e_t[j] = exp(lb_t[j] - m_t).
// Emission: lb = [x^2 ; x] (BTx256) @ Wc (256x64) + cn, via bf16 MFMA 32x32x16,
//           fused row-max/exp -> E (bf16), MV (f32).
// Phase 1: per (batch, chunk of 64 steps) propagate 64x64 matrix
//          D <- diag(e_t) (A^T D) in registers (MFMA + permlane32_swap).
// Phase 2: per batch, fold the 32 chunk matrices sequentially.
//
// ws layout (float units):
//   ATF  @ 0        2048     A^T MFMA A-fragments (32x32x16), per (frag,lane)
//   PI   @ 2048     64       exp(log_softmax(priors))
//   CN   @ 2112     64       -0.5*(t3 + D*log2pi)
//   WBF  @ 2176     8192     Wc B-fragments bf16, [ (Kb*2+J)*64 + lane ] * 4 u32
//   MV   @ 10368    131072   m_t per (b,t)
//   PART @ 141440   64       per-batch final logsumexp
//   GLS  @ 141504   2048     per (b,chunk) log-scale from phase-1 renorms
//   E    @ 143552   4194304  (= 8388608 bf16)  e values [b][t][n]
//   G    @ 4337856  4194304  (= 8388608 bf16)  chunk mats TRANSPOSED [job][new][start]
// total 8532160 floats = 34.1 MB

constexpr int ATF_OFF  = 0;
constexpr int PI_OFF   = 2048;
constexpr int CN_OFF   = 2112;
constexpr int WBF_OFF  = 2176;
constexpr int MV_OFF   = 10368;
constexpr int PART_OFF = 141440;
constexpr int GLS_OFF  = 141504;
constexpr int E_OFF    = 143552;
constexpr int G_OFF    = 4337856;

typedef __attribute__((ext_vector_type(8))) short bf16x8;
typedef __attribute__((ext_vector_type(16))) float f32x16;

union BU { unsigned u[4]; bf16x8 v; };

__device__ inline float wave_max(float v) {
  #pragma unroll
  for (int off = 1; off < 64; off <<= 1) v = fmaxf(v, __shfl_xor(v, off));
  return v;
}
__device__ inline float wave_sum(float v) {
  #pragma unroll
  for (int off = 1; off < 64; off <<= 1) v += __shfl_xor(v, off);
  return v;
}
__device__ inline float read_lane(float v, int l) {
  return __uint_as_float(__builtin_amdgcn_readlane(__float_as_uint(v), l));
}
__device__ inline unsigned f2bf(float f) {   // RNE f32->bf16
  unsigned u = __float_as_uint(f);
  u += 0x7FFFu + ((u >> 16) & 1u);
  return u >> 16;
}
__device__ inline unsigned cvt_pk(float lo, float hi) {  // packed f32x2 -> bf16x2
  unsigned r;
  asm("v_cvt_pk_bf16_f32 %0, %1, %2" : "=v"(r) : "v"(lo), "v"(hi));
  return r;
}

// ---------------- setup: ATF, PI, CN, WBF ----------------
__global__ void setup_kernel(const float* __restrict__ trans,
                             const float* __restrict__ priors,
                             const float* __restrict__ means,
                             const float* __restrict__ log_vars,
                             float* __restrict__ ws) {
  __shared__ float Psh[64 * 64];
  int tid = threadIdx.x, lane = tid & 63, w = tid >> 6;

  // P[i][j] = exp(log_softmax(trans, rows))
  for (int r = 0; r < 16; ++r) {
    int i = w * 16 + r;
    float x = trans[i * 64 + lane];
    float m = wave_max(x);
    float s = wave_sum(__expf(x - m));
    Psh[i * 64 + lane] = __expf(x - (m + __logf(s)));
  }
  if (w == 0) {
    float x = priors[lane];
    float m = wave_max(x);
    float s = wave_sum(__expf(x - m));
    ws[PI_OFF + lane] = __expf(x - (m + __logf(s)));
  }
  // cn[n], 4-way unrolled
  if (tid < 64) {
    int n = tid;
    float s0 = 0.f, s1 = 0.f, s2 = 0.f, s3 = 0.f;
    for (int d = 0; d < 128; d += 4) {
      float lv0 = log_vars[n * 128 + d + 0], mu0 = means[n * 128 + d + 0];
      float lv1 = log_vars[n * 128 + d + 1], mu1 = means[n * 128 + d + 1];
      float lv2 = log_vars[n * 128 + d + 2], mu2 = means[n * 128 + d + 2];
      float lv3 = log_vars[n * 128 + d + 3], mu3 = means[n * 128 + d + 3];
      s0 += mu0 * mu0 * __expf(-lv0) + lv0;
      s1 += mu1 * mu1 * __expf(-lv1) + lv1;
      s2 += mu2 * mu2 * __expf(-lv2) + lv2;
      s3 += mu3 * mu3 * __expf(-lv3) + lv3;
    }
    ws[CN_OFF + n] = -0.5f * ((s0 + s1) + (s2 + s3) + 128.0f * 1.8378770664093453f);
  }
  // WBF: B-fragments of Wc for emis. frag (Kb,J), lane l holds
  // B[k=16Kb+8(l>>5)+j][n=32J+(l&31)], j=0..7, packed pairs (even lo).
  // Wc[k][n] = (k<128) ? -0.5*exp(-lv[n][k]) : mean[n][k-128]*exp(-lv[n][k-128])
  for (int idx = tid; idx < 2048; idx += 256) {
    int f = idx >> 6, l = idx & 63;
    int Kb = f >> 1, J = f & 1;
    int n = 32 * J + (l & 31);
    int kb = 16 * Kb + 8 * (l >> 5);
    unsigned u[4];
    #pragma unroll
    for (int p = 0; p < 4; ++p) {
      int k0 = kb + 2 * p, k1 = k0 + 1;
      int d0 = k0 & 127, d1 = k1 & 127;
      float iv0 = __expf(-log_vars[n * 128 + d0]);
      float iv1 = __expf(-log_vars[n * 128 + d1]);
      float a  = (k0 < 128) ? (-0.5f * iv0) : (means[n * 128 + d0] * iv0);
      float bb = (k1 < 128) ? (-0.5f * iv1) : (means[n * 128 + d1] * iv1);
      u[p] = f2bf(a) | (f2bf(bb) << 16);
    }
    *reinterpret_cast<uint4*>(&ws[WBF_OFF + idx * 4]) = make_uint4(u[0], u[1], u[2], u[3]);
  }
  __syncthreads();
  // ATF: A-operand frags of A^T, frag f = I*4+Kb; lane l holds
  // A_op[m=32I+(l&31)][k=16Kb+8(l>>5)+j] = P[k][m], j=0..7 packed pairs.
  for (int idx = tid; idx < 512; idx += 256) {
    int f = idx >> 6, l = idx & 63;
    int I = f >> 2, Kb = f & 3;
    int m = 32 * I + (l & 31);
    int kb = 16 * Kb + 8 * (l >> 5);
    unsigned u[4];
    #pragma unroll
    for (int p = 0; p < 4; ++p) {
      unsigned a = f2bf(Psh[(kb + 2 * p) * 64 + m]);
      unsigned b = f2bf(Psh[(kb + 2 * p + 1) * 64 + m]);
      u[p] = a | (b << 16);
    }
    *reinterpret_cast<uint4*>(&ws[ATF_OFF + idx * 4]) = make_uint4(u[0], u[1], u[2], u[3]);
  }
}

// ---------------- emissions via MFMA ----------------
// Block = 256 thr (4 waves), covers 128 t-rows; wave w: rows blk*128+32w..+31.
// Wave tile: 32 t x 64 n, K=256 as 16 Kb-steps (Kb<8: x^2 frags, Kb>=8: x frags).
__global__ __launch_bounds__(256) void emis_kernel(const float* __restrict__ X,
                                                   float* __restrict__ ws) {
  __shared__ uint4 WBs[2048];   // 32 KB: all Wc B-frags
  int tid = threadIdx.x;
  const uint4* wbf = reinterpret_cast<const uint4*>(&ws[WBF_OFF]);
  #pragma unroll
  for (int i = 0; i < 8; ++i) WBs[tid + 256 * i] = wbf[tid + 256 * i];

  int lane = tid & 63, w = tid >> 6;
  int il = lane & 31, h = lane >> 5;
  size_t row = (size_t)blockIdx.x * 128 + w * 32 + il;
  const float* Xr = X + row * 128;

  // A-frags: lane holds its row's h-half, 8 segments of 8 floats
  bf16x8 ax[8], asq[8];
  #pragma unroll
  for (int s = 0; s < 8; ++s) {
    float4 v0 = *reinterpret_cast<const float4*>(Xr + s * 16 + 8 * h);
    float4 v1 = *reinterpret_cast<const float4*>(Xr + s * 16 + 8 * h + 4);
    BU bx, bq;
    bx.u[0] = cvt_pk(v0.x, v0.y); bx.u[1] = cvt_pk(v0.z, v0.w);
    bx.u[2] = cvt_pk(v1.x, v1.y); bx.u[3] = cvt_pk(v1.z, v1.w);
    bq.u[0] = cvt_pk(v0.x * v0.x, v0.y * v0.y);
    bq.u[1] = cvt_pk(v0.z * v0.z, v0.w * v0.w);
    bq.u[2] = cvt_pk(v1.x * v1.x, v1.y * v1.y);
    bq.u[3] = cvt_pk(v1.z * v1.z, v1.w * v1.w);
    ax[s] = bx.v; asq[s] = bq.v;
  }
  __syncthreads();

  f32x16 acc0, acc1;
  #pragma unroll
  for (int z = 0; z < 16; ++z) { acc0[z] = 0.f; acc1[z] = 0.f; }
  #pragma unroll
  for (int Kb = 0; Kb < 8; ++Kb) {
    bf16x8 b0 = reinterpret_cast<const BU*>(&WBs[(2 * Kb + 0) * 64 + lane])->v;
    bf16x8 b1 = reinterpret_cast<const BU*>(&WBs[(2 * Kb + 1) * 64 + lane])->v;
    acc0 = __builtin_amdgcn_mfma_f32_32x32x16_bf16(asq[Kb], b0, acc0, 0, 0, 0);
    acc1 = __builtin_amdgcn_mfma_f32_32x32x16_bf16(asq[Kb], b1, acc1, 0, 0, 0);
  }
  #pragma unroll
  for (int Kb = 8; Kb < 16; ++Kb) {
    bf16x8 b0 = reinterpret_cast<const BU*>(&WBs[(2 * Kb + 0) * 64 + lane])->v;
    bf16x8 b1 = reinterpret_cast<const BU*>(&WBs[(2 * Kb + 1) * 64 + lane])->v;
    acc0 = __builtin_amdgcn_mfma_f32_32x32x16_bf16(ax[Kb - 8], b0, acc0, 0, 0, 0);
    acc1 = __builtin_amdgcn_mfma_f32_32x32x16_bf16(ax[Kb - 8], b1, acc1, 0, 0, 0);
  }

  // epilogue: + cn, row max over n (32 lanes x 2 tiles), exp, store E/MV
  float cn0 = ws[CN_OFF + il];
  float cn1 = ws[CN_OFF + 32 + il];
  unsigned short* Ep = reinterpret_cast<unsigned short*>(&ws[E_OFF]);
  float* MVp = &ws[MV_OFF];
  size_t tbase = (size_t)blockIdx.x * 128 + w * 32;
  #pragma unroll
  for (int e = 0; e < 16; ++e) {
    float v0 = acc0[e] + cn0;
    float v1 = acc1[e] + cn1;
    float mx = fmaxf(v0, v1);
    #pragma unroll
    for (int off = 1; off < 32; off <<= 1) mx = fmaxf(mx, __shfl_xor(mx, off));
    int r = (e & 3) + 8 * (e >> 2) + 4 * h;
    size_t t = tbase + r;
    Ep[t * 64 + il]      = (unsigned short)f2bf(__expf(v0 - mx));
    Ep[t * 64 + 32 + il] = (unsigned short)f2bf(__expf(v1 - mx));
    if (il == 0) MVp[t] = mx;
  }
}

// ---------------- phase 1: chunk scan, one wave per (batch, chunk), registers only ----------------
__global__ __launch_bounds__(64, 2) void fwd1_scan(float* __restrict__ ws) {
  const int lane = threadIdx.x;
  const int h = lane >> 5, il = lane & 31;
  const int job = blockIdx.x, b = job >> 5, cch = job & 31;

  bf16x8 atf[8];
  #pragma unroll
  for (int f = 0; f < 8; ++f)
    atf[f] = *reinterpret_cast<const bf16x8*>(&ws[ATF_OFF + (f * 64 + lane) * 4]);

  // D = identity, C-layout: tile (I,J), lane (h,il), reg e:
  //   row = 32I + (e&3)+8(e>>2)+4h, col = 32J + il
  f32x16 c00, c01, c10, c11;
  #pragma unroll
  for (int e = 0; e < 16; ++e) {
    float v = (((e & 3) + 8 * (e >> 2) + 4 * h) == il) ? 1.0f : 0.0f;
    c00[e] = v; c11[e] = v; c01[e] = 0.0f; c10[e] = 0.0f;
  }

  const int tstart = 1 + cch * 64;
  const int len = (cch == 31) ? 63 : 64;
  const char* Eb = (const char*)(ws + E_OFF) + ((size_t)b * 2048 + tstart) * 128;

  float Ls = 0.0f;

#define BUILD_B(dst, Ct, p) {                                        \
    unsigned xe0 = cvt_pk((Ct)[8*(p)+0], (Ct)[8*(p)+1]);             \
    unsigned xe1 = cvt_pk((Ct)[8*(p)+2], (Ct)[8*(p)+3]);             \
    unsigned xo0 = cvt_pk((Ct)[8*(p)+4], (Ct)[8*(p)+5]);             \
    unsigned xo1 = cvt_pk((Ct)[8*(p)+6], (Ct)[8*(p)+7]);             \
    asm("v_permlane32_swap_b32 %0, %1" : "+v"(xe0), "+v"(xo0));      \
    asm("v_permlane32_swap_b32 %0, %1" : "+v"(xe1), "+v"(xo1));      \
    BU bu_; bu_.u[0] = xe0; bu_.u[1] = xe1; bu_.u[2] = xo0; bu_.u[3] = xo1; \
    dst = bu_.v; }

  #pragma unroll 1
  for (int step = 0; step < len; ++step) {
    // e_t: per-lane 8B chunks (I half x quad), L2-resident
    uint2 ew[8];
    #pragma unroll
    for (int q = 0; q < 4; ++q) {
      ew[q]     = *reinterpret_cast<const uint2*>(Eb + 16 * q + 8 * h);
      ew[4 + q] = *reinterpret_cast<const uint2*>(Eb + 64 + 16 * q + 8 * h);
    }
    Eb += 128;

    // B-frags from current C (C dies here -> regs reusable as accumulators)
    bf16x8 b00, b10, b20, b30, b01, b11, b21, b31;   // bKb_J
    BUILD_B(b00, c00, 0) BUILD_B(b10, c00, 1)
    BUILD_B(b20, c10, 0) BUILD_B(b30, c10, 1)
    BUILD_B(b01, c01, 0) BUILD_B(b11, c01, 1)
    BUILD_B(b21, c11, 0) BUILD_B(b31, c11, 1)

    // I = 0
    {
      f32x16 a0, a1;
      #pragma unroll
      for (int z = 0; z < 16; ++z) { a0[z] = 0.f; a1[z] = 0.f; }
      a0 = __builtin_amdgcn_mfma_f32_32x32x16_bf16(atf[0], b00, a0, 0, 0, 0);
      a0 = __builtin_amdgcn_mfma_f32_32x32x16_bf16(atf[1], b10, a0, 0, 0, 0);
      a0 = __builtin_amdgcn_mfma_f32_32x32x16_bf16(atf[2], b20, a0, 0, 0, 0);
      a0 = __builtin_amdgcn_mfma_f32_32x32x16_bf16(atf[3], b30, a0, 0, 0, 0);
      a1 = __builtin_amdgcn_mfma_f32_32x32x16_bf16(atf[0], b01, a1, 0, 0, 0);
      a1 = __builtin_amdgcn_mfma_f32_32x32x16_bf16(atf[1], b11, a1, 0, 0, 0);
      a1 = __builtin_amdgcn_mfma_f32_32x32x16_bf16(atf[2], b21, a1, 0, 0, 0);
      a1 = __builtin_amdgcn_mfma_f32_32x32x16_bf16(atf[3], b31, a1, 0, 0, 0);
      #pragma unroll
      for (int z = 0; z < 16; ++z) {
        uint2 u2 = ew[z >> 2];
        unsigned uu = ((z >> 1) & 1) ? u2.y : u2.x;
        float s = __uint_as_float((z & 1) ? (uu & 0xFFFF0000u) : (uu << 16));
        c00[z] = a0[z] * s; c01[z] = a1[z] * s;
      }
    }
    // I = 1
    {
      f32x16 a0, a1;
      #pragma unroll
      for (int z = 0; z < 16; ++z) { a0[z] = 0.f; a1[z] = 0.f; }
      a0 = __builtin_amdgcn_mfma_f32_32x32x16_bf16(atf[4], b00, a0, 0, 0, 0);
      a0 = __builtin_amdgcn_mfma_f32_32x32x16_bf16(atf[5], b10, a0, 0, 0, 0);
      a0 = __builtin_amdgcn_mfma_f32_32x32x16_bf16(atf[6], b20, a0, 0, 0, 0);
      a0 = __builtin_amdgcn_mfma_f32_32x32x16_bf16(atf[7], b30, a0, 0, 0, 0);
      a1 = __builtin_amdgcn_mfma_f32_32x32x16_bf16(atf[4], b01, a1, 0, 0, 0);
      a1 = __builtin_amdgcn_mfma_f32_32x32x16_bf16(atf[5], b11, a1, 0, 0, 0);
      a1 = __builtin_amdgcn_mfma_f32_32x32x16_bf16(atf[6], b21, a1, 0, 0, 0);
      a1 = __builtin_amdgcn_mfma_f32_32x32x16_bf16(atf[7], b31, a1, 0, 0, 0);
      #pragma unroll
      for (int z = 0; z < 16; ++z) {
        uint2 u2 = ew[4 + (z >> 2)];
        unsigned uu = ((z >> 1) & 1) ? u2.y : u2.x;
        float s = __uint_as_float((z & 1) ? (uu & 0xFFFF0000u) : (uu << 16));
        c10[z] = a0[z] * s; c11[z] = a1[z] * s;
      }
    }

    // max-entry renorm every 8 steps (exact; absorbed into Ls)
    if ((step & 7) == 7) {
      float mx = 0.f;
      #pragma unroll
      for (int z = 0; z < 16; ++z)
        mx = fmaxf(mx, fmaxf(fmaxf(c00[z], c01[z]), fmaxf(c10[z], c11[z])));
      mx = wave_max(mx);
      float inv = 1.0f / mx;
      Ls += __logf(mx);
      #pragma unroll
      for (int z = 0; z < 16; ++z) {
        c00[z] *= inv; c01[z] *= inv; c10[z] *= inv; c11[z] *= inv;
      }
    }
  }
#undef BUILD_B

  // store G TRANSPOSED: GT[new m][start n] = C[m][n]  (bf16)
  unsigned short* Gb = reinterpret_cast<unsigned short*>(&ws[G_OFF]) + (size_t)job * 4096;
#define STORE_T(Ct, I, J) {                                          \
    _Pragma("unroll")                                                \
    for (int e = 0; e < 16; ++e) {                                   \
      int m = 32 * (I) + (e & 3) + 8 * (e >> 2) + 4 * h;             \
      Gb[m * 64 + 32 * (J) + il] = (unsigned short)f2bf((Ct)[e]);    \
    } }
  STORE_T(c00, 0, 0) STORE_T(c01, 0, 1) STORE_T(c10, 1, 0) STORE_T(c11, 1, 1)
#undef STORE_T
  if (lane == 0) ws[GLS_OFF + job] = Ls;
}

// ---------------- phase 2: fold 32 chunk matrices per batch ----------------
__global__ __launch_bounds__(64, 1) void fwd2_combine(float* __restrict__ ws) {
  int b = blockIdx.x, j = threadIdx.x;

  float Ms = 0.f;
  for (int k = 0; k < 32; ++k) Ms += ws[MV_OFF + (size_t)b * 2048 + k * 64 + j];
  Ms = wave_sum(Ms);

  const unsigned short* E0 =
      reinterpret_cast<const unsigned short*>(&ws[E_OFF]) + (size_t)b * 2048 * 64;
  float w = ws[PI_OFF + j] * __uint_as_float(((unsigned)E0[j]) << 16);
  float Lacc = Ms;

  const unsigned short* Gb =
      reinterpret_cast<const unsigned short*>(&ws[G_OFF]) + (size_t)b * 32 * 4096;
  for (int c = 0; c < 32; ++c) {
    // lane j reads GT row j: T[i][j] = GT[j][i], contiguous 128 B
    const uint4* gp = reinterpret_cast<const uint4*>(Gb + (size_t)c * 4096 + j * 64);
    uint4 gw[8];
    #pragma unroll
    for (int s = 0; s < 8; ++s) gw[s] = gp[s];
    float gv[64];
    #pragma unroll
    for (int s = 0; s < 8; ++s) {
      gv[8 * s + 0] = __uint_as_float(gw[s].x << 16);
      gv[8 * s + 1] = __uint_as_float(gw[s].x & 0xFFFF0000u);
      gv[8 * s + 2] = __uint_as_float(gw[s].y << 16);
      gv[8 * s + 3] = __uint_as_float(gw[s].y & 0xFFFF0000u);
      gv[8 * s + 4] = __uint_as_float(gw[s].z << 16);
      gv[8 * s + 5] = __uint_as_float(gw[s].z & 0xFFFF0000u);
      gv[8 * s + 6] = __uint_as_float(gw[s].w << 16);
      gv[8 * s + 7] = __uint_as_float(gw[s].w & 0xFFFF0000u);
    }
    float a0 = 0.f, a1 = 0.f, a2 = 0.f, a3 = 0.f;
    #pragma unroll
    for (int i = 0; i < 64; i += 4) {
      a0 = fmaf(read_lane(w, i + 0), gv[i + 0], a0);
      a1 = fmaf(read_lane(w, i + 1), gv[i + 1], a1);
      a2 = fmaf(read_lane(w, i + 2), gv[i + 2], a2);
      a3 = fmaf(read_lane(w, i + 3), gv[i + 3], a3);
    }
    float y = (a0 + a1) + (a2 + a3);
    float s = wave_sum(y);
    w = y * (1.0f / s);
    Lacc += __logf(s) + ws[GLS_OFF + b * 32 + c];
  }
  float S = wave_sum(w);
  if (j == 0) ws[PART_OFF + b] = Lacc + __logf(S);
}

// ---------------- final deterministic sum ----------------
__global__ void final_kernel(const float* __restrict__ part, float* __restrict__ out) {
  float v = part[threadIdx.x];
  float s = wave_sum(v);
  if (threadIdx.x == 0) out[0] = s;
}

extern "C" void kernel_launch(void* const* d_in, const int* in_sizes, int n_in,
                              void* d_out, int out_size, void* d_ws, size_t ws_size,
                              hipStream_t stream) {
  const float* X        = (const float*)d_in[0];
  const float* trans    = (const float*)d_in[1];
  const float* priors   = (const float*)d_in[2];
  const float* means    = (const float*)d_in[3];
  const float* log_vars = (const float*)d_in[4];
  float* ws  = (float*)d_ws;
  float* out = (float*)d_out;

  hipLaunchKernelGGL(setup_kernel, dim3(1), dim3(256), 0, stream,
                     trans, priors, means, log_vars, ws);
  hipLaunchKernelGGL(emis_kernel, dim3(1024), dim3(256), 0, stream, X, ws);
  hipLaunchKernelGGL(fwd1_scan, dim3(2048), dim3(64), 0, stream, ws);
  hipLaunchKernelGGL(fwd2_combine, dim3(64), dim3(64), 0, stream, ws);
  hipLaunchKernelGGL(final_kernel, dim3(1), dim3(64), 0, stream,
                     ws + PART_OFF, out);
}